// Round 2
// baseline (2441.880 us; speedup 1.0000x reference)
//
#include <hip/hip_runtime.h>

#define PTS     2048
#define NBATCH  8
#define NPROB   24          // 8 xy + 8 xx + 8 yy
#define JC      4           // column chunks (partial sums)
#define CHUNK   (PTS / JC)  // 512
#define THREADS 256
#define RG      (PTS / THREADS)   // 8 row groups
#define MAX_ITER 20

// k(x,y) = exp(-2*acos(min(|x.y|, 1-1e-7))/0.05) = 2^(-57.7078016 * acos(t))
#define EXP_SCALE (-57.70780163555853f)   // -(2/0.05)*log2(e)
#define EPS_LN2   (0.034657359027997264f) // 0.05 * ln(2)

// acos(t) = sqrt(1-t) * poly(t), |err| <= 2e-8 on [0,1]  (A&S 4.4.45 style)
__device__ __forceinline__ float acos_poly(float t) {
    float p = -0.0012624911f;
    p = fmaf(p, t,  0.0066700901f);
    p = fmaf(p, t, -0.0170881256f);
    p = fmaf(p, t,  0.0308918810f);
    p = fmaf(p, t, -0.0501743046f);
    p = fmaf(p, t,  0.0889789874f);
    p = fmaf(p, t, -0.2145988016f);
    p = fmaf(p, t,  1.5707963050f);
    return p;
}

// problem p: type = p>>3 (0:xy 1:xx 2:yy), batch n = p&7
// X-side (row potentials f/u, weights a), Y-side (col potentials g/v, weights b)
__device__ __forceinline__ void prob_ptrs(int p,
        const float* x, const float* y, const float* wx, const float* wy,
        const float** Xp, const float** Yp, const float** wa, const float** wb) {
    int type = p >> 3, n = p & 7;
    *Xp = ((type <= 1) ? x : y) + (size_t)n * PTS * 4;
    *Yp = ((type == 0) ? y : ((type == 1) ? x : y)) + (size_t)n * PTS * 4;
    *wa = ((type <= 1) ? wx : wy) + (size_t)n * PTS;
    *wb = ((type == 0) ? wy : ((type == 1) ? wx : wy)) + (size_t)n * PTS;
}

// partials layout: part[p][jc][row], row-sums are sum over jc.
// Init: part[p][0][i] = 1, rest 0  ->  lw = log2(w) - log2(1) = log2(w)  (f = 0 start)
__global__ void __launch_bounds__(THREADS) init_partials(float* __restrict__ partA) {
    int i = blockIdx.x * THREADS + threadIdx.x;   // over NPROB*PTS
    int p = i / PTS, r = i % PTS;
    float* base = partA + (size_t)p * JC * PTS;
    base[0 * PTS + r] = 1.0f;
    base[1 * PTS + r] = 0.0f;
    base[2 * PTS + r] = 0.0f;
    base[3 * PTS + r] = 0.0f;
}

// One half-update (side 0: g/v-update — rows are Y pts, cols are X pts, col-weights a;
//                  side 1: f/u-update — rows are X pts, cols are Y pts, col-weights b).
// Writes partial row-sums: part_out[p][jc][r] = sum_{j in chunk jc} 2^(EXP_SCALE*acos(t_rj) + lw_j)
// where lw_j = log2(w_col_j) - log2(sum_jc part_in[p][jc][j])  (fused combine of prev update).
__global__ void __launch_bounds__(THREADS) half_update(
        const float* __restrict__ x,  const float* __restrict__ y,
        const float* __restrict__ wx, const float* __restrict__ wy,
        const float* __restrict__ part_in, float* __restrict__ part_out, int side)
{
    __shared__ float4 cpts[CHUNK];
    __shared__ float  clw[CHUNK];

    int b  = blockIdx.x;
    int p  = b >> 5;          // RG*JC = 32 blocks per problem
    int rg = (b >> 2) & 7;
    int jc = b & 3;

    const float *Xp, *Yp, *wa, *wb;
    prob_ptrs(p, x, y, wx, wy, &Xp, &Yp, &wa, &wb);
    const float* rowPts = (side == 0) ? Yp : Xp;
    const float* colPts = (side == 0) ? Xp : Yp;
    const float* wcol   = (side == 0) ? wa : wb;

    // prologue: combine prev partials -> lw, stage column points
    const float* pin = part_in + (size_t)p * JC * PTS;
    for (int k = threadIdx.x; k < CHUNK; k += THREADS) {
        int j = jc * CHUNK + k;
        float s = pin[0 * PTS + j] + pin[1 * PTS + j] + pin[2 * PTS + j] + pin[3 * PTS + j];
        clw[k]  = __log2f(wcol[j]) - __log2f(s);
        cpts[k] = reinterpret_cast<const float4*>(colPts)[j];
    }
    __syncthreads();

    int r = rg * THREADS + threadIdx.x;
    float4 rp = reinterpret_cast<const float4*>(rowPts)[r];
    float acc = 0.0f;
    #pragma unroll 8
    for (int k = 0; k < CHUNK; ++k) {
        float4 q = cpts[k];                 // LDS broadcast (same addr across wave)
        float d = rp.x * q.x;
        d = fmaf(rp.y, q.y, d);
        d = fmaf(rp.z, q.z, d);
        d = fmaf(rp.w, q.w, d);
        float t  = fminf(fabsf(d), 0.9999999f);      // clip(|.|, 0, 1-1e-7) in f32
        float sr = __builtin_amdgcn_sqrtf(1.0f - t); // v_sqrt_f32
        float A  = sr * acos_poly(t);                // acos(t)
        acc += exp2f(fmaf(A, EXP_SCALE, clw[k]));    // k(x,y) * w_j, log2-folded
    }
    part_out[((size_t)p * JC + jc) * PTS + r] = acc;
}

// OT_p = sum_i a_i f_i + sum_j b_j g_j = -eps*ln2*( sum_i a_i log2(rsA_i) + sum_j b_j log2(rsB_j) )
__global__ void __launch_bounds__(THREADS) ot_reduce(
        const float* __restrict__ x,  const float* __restrict__ y,
        const float* __restrict__ wx, const float* __restrict__ wy,
        const float* __restrict__ partA, const float* __restrict__ partB,
        float* __restrict__ ot)
{
    int p = blockIdx.x;
    const float *Xp, *Yp, *wa, *wb;
    prob_ptrs(p, x, y, wx, wy, &Xp, &Yp, &wa, &wb);
    const float* pa = partA + (size_t)p * JC * PTS;
    const float* pb = partB + (size_t)p * JC * PTS;

    float acc = 0.0f;
    for (int i = threadIdx.x; i < PTS; i += THREADS) {
        float rsA = pa[0*PTS+i] + pa[1*PTS+i] + pa[2*PTS+i] + pa[3*PTS+i];
        float rsB = pb[0*PTS+i] + pb[1*PTS+i] + pb[2*PTS+i] + pb[3*PTS+i];
        acc += wa[i] * __log2f(rsA) + wb[i] * __log2f(rsB);
    }
    // block reduce: wave shfl, then LDS across 4 waves
    for (int off = 32; off; off >>= 1) acc += __shfl_down(acc, off, 64);
    __shared__ float red[THREADS / 64];
    if ((threadIdx.x & 63) == 0) red[threadIdx.x >> 6] = acc;
    __syncthreads();
    if (threadIdx.x == 0) {
        float t = red[0] + red[1] + red[2] + red[3];
        ot[p] = -EPS_LN2 * t;
    }
}

__global__ void combine(const float* __restrict__ ot, float* __restrict__ out) {
    if (threadIdx.x == 0) {
        float s = 0.0f;
        for (int n = 0; n < NBATCH; ++n)
            s += ot[n] - 0.5f * (ot[8 + n] + ot[16 + n]);
        out[0] = s / (float)NBATCH;
    }
}

extern "C" void kernel_launch(void* const* d_in, const int* in_sizes, int n_in,
                              void* d_out, int out_size, void* d_ws, size_t ws_size,
                              hipStream_t stream)
{
    // setup_inputs dict order: y, w_y, x, w_x
    const float* y  = (const float*)d_in[0];
    const float* wy = (const float*)d_in[1];
    const float* x  = (const float*)d_in[2];
    const float* wx = (const float*)d_in[3];
    float* out = (float*)d_out;

    float* partA = (float*)d_ws;                       // [NPROB][JC][PTS] f32 (u/f side)
    float* partB = partA + (size_t)NPROB * JC * PTS;   // [NPROB][JC][PTS] f32 (v/g side)
    float* ot    = partB + (size_t)NPROB * JC * PTS;   // [NPROB] f32
    // total ws need: 2*24*4*2048*4 + 96 bytes ~= 1.6 MB

    init_partials<<<NPROB * PTS / THREADS, THREADS, 0, stream>>>(partA);
    for (int it = 0; it < MAX_ITER; ++it) {
        half_update<<<NPROB * RG * JC, THREADS, 0, stream>>>(x, y, wx, wy, partA, partB, 0);
        half_update<<<NPROB * RG * JC, THREADS, 0, stream>>>(x, y, wx, wy, partB, partA, 1);
    }
    ot_reduce<<<NPROB, THREADS, 0, stream>>>(x, y, wx, wy, partA, partB, ot);
    combine<<<1, 64, 0, stream>>>(ot, out);
}

// Round 3
// 1600.767 us; speedup vs baseline: 1.5254x; 1.5254x over previous
//
#include <hip/hip_runtime.h>

#define PTS     2048
#define NBATCH  8
#define NPROB   24          // 8 xy + 8 xx + 8 yy
#define THREADS 256
#define MR      2           // rows per thread (amortize LDS broadcast + enable pk-f32)
#define ROWSPB  (THREADS * MR)      // 512 rows per block
#define RG      (PTS / ROWSPB)      // 4 row groups
#define MAX_ITER 20

// k(x,y) = exp(-2*acos(min(|x.y|, 1-1e-7))/0.05) = 2^(-57.7078016 * acos(t))
#define EXP_SCALE (-57.70780163555853f)   // -(2/0.05)*log2(e)
#define EPS_LN2   (0.034657359027997264f) // 0.05 * ln(2)
#define CLIP      (0.9999999f)

// acos(t) = sqrt(1-t) * poly(t), |err| <= 6.8e-5 on [0,1]  (A&S 4.4.45, 4-term)
// error budget: dk/k = 57.7*ln2*6.8e-5 ~ 0.27% -> OT err ~1e-4 << 4e-3 threshold
__device__ __forceinline__ float acos_poly(float t) {
    float p = -0.0187292994f;
    p = fmaf(p, t,  0.0742610022f);
    p = fmaf(p, t, -0.2121143937f);
    p = fmaf(p, t,  1.5707287550f);
    return p;
}

// problem p: type = p>>3 (0:xy 1:xx 2:yy), batch n = p&7
__device__ __forceinline__ void prob_ptrs(int p,
        const float* x, const float* y, const float* wx, const float* wy,
        const float** Xp, const float** Yp, const float** wa, const float** wb) {
    int type = p >> 3, n = p & 7;
    *Xp = ((type <= 1) ? x : y) + (size_t)n * PTS * 4;
    *Yp = ((type == 0) ? y : ((type == 1) ? x : y)) + (size_t)n * PTS * 4;
    *wa = ((type <= 1) ? wx : wy) + (size_t)n * PTS;
    *wb = ((type == 0) ? wy : ((type == 1) ? wx : wy)) + (size_t)n * PTS;
}

// partials layout: part[p][jc][row]; row-sum = sum over jc.
// Init: part[p][0][i]=1, rest 0 -> lw = log2(w) - log2(1) (f = 0 start)
template <int JCv>
__global__ void __launch_bounds__(THREADS) init_partials(float* __restrict__ partA) {
    int i = blockIdx.x * THREADS + threadIdx.x;   // over NPROB*PTS
    int p = i / PTS, r = i % PTS;
    float* base = partA + (size_t)p * JCv * PTS;
    base[r] = 1.0f;
    #pragma unroll
    for (int c = 1; c < JCv; ++c) base[c * PTS + r] = 0.0f;
}

// One half-update. side 0: g/v-update (rows = Y pts, cols = X pts, col-weights a);
//                  side 1: f/u-update (rows = X pts, cols = Y pts, col-weights b).
// part_out[p][jc][r] = sum_{j in chunk jc} 2^(EXP_SCALE*acos(t_rj) + lw_j),
// lw_j = log2(w_col_j) - log2(sum_c part_in[p][c][j])   (fused combine of prev half)
template <int JCv>
__global__ void __launch_bounds__(THREADS) half_update(
        const float* __restrict__ x,  const float* __restrict__ y,
        const float* __restrict__ wx, const float* __restrict__ wy,
        const float* __restrict__ part_in, float* __restrict__ part_out, int side)
{
    constexpr int CHUNK = PTS / JCv;
    __shared__ float4 cpts[CHUNK];
    __shared__ float  clw[CHUNK];

    int b   = blockIdx.x;
    int p   = b / (RG * JCv);
    int rem = b % (RG * JCv);
    int rg  = rem / JCv;
    int jc  = rem % JCv;

    const float *Xp, *Yp, *wa, *wb;
    prob_ptrs(p, x, y, wx, wy, &Xp, &Yp, &wa, &wb);
    const float* rowPts = (side == 0) ? Yp : Xp;
    const float* colPts = (side == 0) ? Xp : Yp;
    const float* wcol   = (side == 0) ? wa : wb;

    // prologue: combine prev partials -> lw, stage column points
    const float* pin = part_in + (size_t)p * JCv * PTS;
    for (int k = threadIdx.x; k < CHUNK; k += THREADS) {
        int j = jc * CHUNK + k;
        float s = 0.0f;
        #pragma unroll
        for (int c = 0; c < JCv; ++c) s += pin[c * PTS + j];
        clw[k]  = __builtin_amdgcn_logf(wcol[j]) - __builtin_amdgcn_logf(s);
        cpts[k] = reinterpret_cast<const float4*>(colPts)[j];
    }
    __syncthreads();

    int r0 = rg * ROWSPB + threadIdx.x;     // two rows per thread, stride THREADS
    int r1 = r0 + THREADS;
    float4 ra = reinterpret_cast<const float4*>(rowPts)[r0];
    float4 rb = reinterpret_cast<const float4*>(rowPts)[r1];
    float acc0 = 0.0f, acc1 = 0.0f;
    #pragma unroll 4
    for (int k = 0; k < CHUNK; ++k) {
        float4 q = cpts[k];                 // LDS same-address broadcast
        float lw = clw[k];
        float d0 = ra.x * q.x;              // dual-row: SLP can pack to v_pk_fma_f32
        float d1 = rb.x * q.x;
        d0 = fmaf(ra.y, q.y, d0);  d1 = fmaf(rb.y, q.y, d1);
        d0 = fmaf(ra.z, q.z, d0);  d1 = fmaf(rb.z, q.z, d1);
        d0 = fmaf(ra.w, q.w, d0);  d1 = fmaf(rb.w, q.w, d1);
        float t0 = fminf(fabsf(d0), CLIP);
        float t1 = fminf(fabsf(d1), CLIP);
        float s0 = __builtin_amdgcn_sqrtf(1.0f - t0);   // v_sqrt_f32
        float s1 = __builtin_amdgcn_sqrtf(1.0f - t1);
        float A0 = s0 * acos_poly(t0);
        float A1 = s1 * acos_poly(t1);
        acc0 += __builtin_amdgcn_exp2f(fmaf(A0, EXP_SCALE, lw));  // v_exp_f32
        acc1 += __builtin_amdgcn_exp2f(fmaf(A1, EXP_SCALE, lw));
    }
    float* pout = part_out + ((size_t)p * JCv + jc) * PTS;
    pout[r0] = acc0;
    pout[r1] = acc1;
}

// OT_p = -eps*ln2*( sum_i a_i log2(rsA_i) + sum_j b_j log2(rsB_j) )
template <int JCv>
__global__ void __launch_bounds__(THREADS) ot_reduce(
        const float* __restrict__ x,  const float* __restrict__ y,
        const float* __restrict__ wx, const float* __restrict__ wy,
        const float* __restrict__ partA, const float* __restrict__ partB,
        float* __restrict__ ot)
{
    int p = blockIdx.x;
    const float *Xp, *Yp, *wa, *wb;
    prob_ptrs(p, x, y, wx, wy, &Xp, &Yp, &wa, &wb);
    const float* pa = partA + (size_t)p * JCv * PTS;
    const float* pb = partB + (size_t)p * JCv * PTS;

    float acc = 0.0f;
    for (int i = threadIdx.x; i < PTS; i += THREADS) {
        float rsA = 0.0f, rsB = 0.0f;
        #pragma unroll
        for (int c = 0; c < JCv; ++c) { rsA += pa[c*PTS+i]; rsB += pb[c*PTS+i]; }
        acc += wa[i] * __builtin_amdgcn_logf(rsA) + wb[i] * __builtin_amdgcn_logf(rsB);
    }
    for (int off = 32; off; off >>= 1) acc += __shfl_down(acc, off, 64);
    __shared__ float red[THREADS / 64];
    if ((threadIdx.x & 63) == 0) red[threadIdx.x >> 6] = acc;
    __syncthreads();
    if (threadIdx.x == 0) {
        float t = red[0] + red[1] + red[2] + red[3];
        ot[p] = -EPS_LN2 * t;
    }
}

__global__ void combine(const float* __restrict__ ot, float* __restrict__ out) {
    if (threadIdx.x == 0) {
        float s = 0.0f;
        for (int n = 0; n < NBATCH; ++n)
            s += ot[n] - 0.5f * (ot[8 + n] + ot[16 + n]);
        out[0] = s / (float)NBATCH;
    }
}

template <int JCv>
static void run_all(const float* x, const float* y, const float* wx, const float* wy,
                    float* out, void* d_ws, hipStream_t stream)
{
    float* partA = (float*)d_ws;                        // [NPROB][JCv][PTS]
    float* partB = partA + (size_t)NPROB * JCv * PTS;   // [NPROB][JCv][PTS]
    float* ot    = partB + (size_t)NPROB * JCv * PTS;   // [NPROB]

    init_partials<JCv><<<NPROB * PTS / THREADS, THREADS, 0, stream>>>(partA);
    for (int it = 0; it < MAX_ITER; ++it) {
        half_update<JCv><<<NPROB * RG * JCv, THREADS, 0, stream>>>(x, y, wx, wy, partA, partB, 0);
        half_update<JCv><<<NPROB * RG * JCv, THREADS, 0, stream>>>(x, y, wx, wy, partB, partA, 1);
    }
    ot_reduce<JCv><<<NPROB, THREADS, 0, stream>>>(x, y, wx, wy, partA, partB, ot);
    combine<<<1, 64, 0, stream>>>(ot, out);
}

extern "C" void kernel_launch(void* const* d_in, const int* in_sizes, int n_in,
                              void* d_out, int out_size, void* d_ws, size_t ws_size,
                              hipStream_t stream)
{
    // setup_inputs dict order: y, w_y, x, w_x
    const float* y  = (const float*)d_in[0];
    const float* wy = (const float*)d_in[1];
    const float* x  = (const float*)d_in[2];
    const float* wx = (const float*)d_in[3];
    float* out = (float*)d_out;

    size_t need8 = ((size_t)2 * NPROB * 8 * PTS + NPROB) * sizeof(float); // ~3.15 MB
    if (ws_size >= need8)
        run_all<8>(x, y, wx, wy, out, d_ws, stream);
    else
        run_all<4>(x, y, wx, wy, out, d_ws, stream);    // ws fallback (~1.6 MB)
}

// Round 5
// 1448.084 us; speedup vs baseline: 1.6863x; 1.1054x over previous
//
#include <hip/hip_runtime.h>
#include <hip/hip_fp16.h>

#define PTS     2048
#define NBATCH  8
#define NPROB   24          // 8 xy + 8 xx + 8 yy
#define NSTRUCT 32          // 24 originals + 8 yx transposes (for xy side-0)
#define THREADS 256
#define MAX_ITER 20

// k(x,y) = exp(-2*acos(min(|x.y|,1-1e-7))/0.05) = 2^(EXP_SCALE * acos(t))
#define EXP_SCALE (-57.70780163555853f)   // -(2/0.05)*log2(e)
#define EPS_LN2   (0.034657359027997264f) // 0.05 * ln(2)
#define CLIP      (0.9999999f)

// Sparsity cutoff: keep entries with L > -44  (theta < 44/57.7078 = 0.76246 rad)
// t > cos(0.76246) = 0.7231383. Culled mass vs worst isolated-row NN (0.21 rad):
// 2048 * 2^(-44+12) * e^(g-range/eps ~ 8) ~ 1.6e-3 relative -> f err ~8e-5. Safe.
#define T_CUT     (0.7231383f)
#define CAP_ENTRIES (28u*1024u*1024u)     // 28M entries (expect ~22.5M) = 112 MB

// acos(t) = sqrt(1-t)*poly(t), |err| <= 6.8e-5 on [0,1] (A&S 4.4.45 4-term)
__device__ __forceinline__ float acos_poly(float t) {
    float p = -0.0187292994f;
    p = fmaf(p, t,  0.0742610022f);
    p = fmaf(p, t, -0.2121143937f);
    p = fmaf(p, t,  1.5707287550f);
    return p;
}

__device__ __forceinline__ unsigned short f32_to_f16bits(float f) {
    __half h = __float2half(f);
    return *reinterpret_cast<unsigned short*>(&h);
}
__device__ __forceinline__ float f16bits_to_f32(unsigned short u) {
    __half h = *reinterpret_cast<__half*>(&u);
    return __half2float(h);
}

// problem p: type=p>>3 (0:xy 1:xx 2:yy), batch n=p&7.
// X-side = rows (f/u potentials, weights a), Y-side = cols (g/v, weights b)
__device__ __forceinline__ void prob_w(int p, const float* wx, const float* wy,
                                       const float** wa, const float** wb) {
    int type = p >> 3, n = p & 7;
    *wa = ((type <= 1) ? wx : wy) + (size_t)n * PTS;
    *wb = ((type == 0) ? wy : ((type == 1) ? wx : wy)) + (size_t)n * PTS;
}

// structure s: s<24 -> CSR of K_p (rows = X-side, cols = Y-side); s in [24,32) ->
// CSR of K_{yx,n} (rows = y_n, cols = x_n), the transpose used for xy side-0.
__device__ __forceinline__ void struct_ptrs(int s,
        const float* x, const float* y, const float** rowP, const float** colP) {
    if (s < 24) {
        int type = s >> 3, n = s & 7;
        *rowP = ((type <= 1) ? x : y) + (size_t)n * PTS * 4;
        *colP = ((type == 0) ? y : ((type == 1) ? x : y)) + (size_t)n * PTS * 4;
    } else {
        int n = s - 24;
        *rowP = y + (size_t)n * PTS * 4;
        *colP = x + (size_t)n * PTS * 4;
    }
}

// ---------------- sparse-cache path ----------------

// rs_f = 1, ratio_f = a  (f = 0 start)
__global__ void __launch_bounds__(THREADS) init_state(
        const float* __restrict__ wx, const float* __restrict__ wy,
        float* __restrict__ rs_f, float* __restrict__ ratio_f) {
    int i = blockIdx.x * THREADS + threadIdx.x;   // over NPROB*PTS
    int p = i / PTS, r = i % PTS;
    const float *wa, *wb;
    prob_w(p, wx, wy, &wa, &wb);
    rs_f[i] = 1.0f;
    ratio_f[i] = wa[r];
}

// one wave per (struct,row): count columns with t > T_CUT
__global__ void __launch_bounds__(THREADS) count_kernel(
        const float* __restrict__ x, const float* __restrict__ y,
        unsigned* __restrict__ counts) {
    int w = (blockIdx.x * THREADS + threadIdx.x) >> 6;
    int lane = threadIdx.x & 63;
    int s = w >> 11, r = w & 2047;
    const float *rowP, *colP;
    struct_ptrs(s, x, y, &rowP, &colP);
    float4 rp = reinterpret_cast<const float4*>(rowP)[r];
    unsigned cnt = 0;
    for (int base = 0; base < PTS; base += 64) {
        float4 q = reinterpret_cast<const float4*>(colP)[base + lane];
        float d = rp.x*q.x; d = fmaf(rp.y,q.y,d); d = fmaf(rp.z,q.z,d); d = fmaf(rp.w,q.w,d);
        float t = fminf(fabsf(d), CLIP);
        cnt += (unsigned)__popcll(__ballot(t > T_CUT));
    }
    if (lane == 0) counts[s * PTS + r] = cnt;
}

// exclusive scan of 2048 counts per structure -> row_start_local + struct_total
__global__ void __launch_bounds__(THREADS) scan_kernel(
        const unsigned* __restrict__ counts, unsigned* __restrict__ rsl,
        unsigned* __restrict__ stotal) {
    int s = blockIdx.x, tid = threadIdx.x;
    const unsigned* c = counts + (size_t)s * PTS;
    unsigned v[8], sum = 0;
    #pragma unroll
    for (int q = 0; q < 8; ++q) { v[q] = c[tid*8+q]; sum += v[q]; }
    __shared__ unsigned ts[THREADS];
    ts[tid] = sum; __syncthreads();
    for (int off = 1; off < THREADS; off <<= 1) {
        unsigned add = (tid >= off) ? ts[tid-off] : 0u;
        __syncthreads();
        ts[tid] += add; __syncthreads();
    }
    unsigned run = (tid == 0) ? 0u : ts[tid-1];
    unsigned* out = rsl + (size_t)s * PTS;
    #pragma unroll
    for (int q = 0; q < 8; ++q) { out[tid*8+q] = run; run += v[q]; }
    if (tid == THREADS-1) stotal[s] = ts[THREADS-1];
}

__global__ void base_kernel(const unsigned* __restrict__ stotal,
                            unsigned* __restrict__ sbase) {
    if (threadIdx.x == 0) {
        unsigned run = 0;
        for (int s = 0; s < NSTRUCT; ++s) { sbase[s] = run; run += stotal[s]; }
    }
}

// ordered compacted fill: entry = (col_idx<<16) | f16(L)
__global__ void __launch_bounds__(THREADS) fill_kernel(
        const float* __restrict__ x, const float* __restrict__ y,
        const unsigned* __restrict__ rsl, const unsigned* __restrict__ sbase,
        unsigned* __restrict__ slab) {
    int w = (blockIdx.x * THREADS + threadIdx.x) >> 6;
    int lane = threadIdx.x & 63;
    int s = w >> 11, r = w & 2047;
    const float *rowP, *colP;
    struct_ptrs(s, x, y, &rowP, &colP);
    float4 rp = reinterpret_cast<const float4*>(rowP)[r];
    unsigned off = sbase[s] + rsl[s * PTS + r];
    // bits [0, lane) -- strictly-lower active lanes. (1ull<<lane)-1 is
    // well-defined for lane 0..63; previous `~0ull` at lane 63 wrongly
    // included the lane's own bit (off-by-one slot + poison hole).
    unsigned long long lt_mask = (1ull << lane) - 1ull;
    for (int base = 0; base < PTS; base += 64) {
        int j = base + lane;
        float4 q = reinterpret_cast<const float4*>(colP)[j];
        float d = rp.x*q.x; d = fmaf(rp.y,q.y,d); d = fmaf(rp.z,q.z,d); d = fmaf(rp.w,q.w,d);
        float t = fminf(fabsf(d), CLIP);
        bool pass = t > T_CUT;
        unsigned long long bal = __ballot(pass);
        if (pass) {
            float sr = __builtin_amdgcn_sqrtf(1.0f - t);
            float L  = EXP_SCALE * (sr * acos_poly(t));
            unsigned pos = off + (unsigned)__popcll(bal & lt_mask);
            if (pos < CAP_ENTRIES)
                slab[pos] = ((unsigned)j << 16) | f32_to_f16bits(L);
        }
        off += (unsigned)__popcll(bal);
    }
}

// one wave per (prob,row): rs = sum_k exp2(L_k)*ratio_src[idx_k]; write rs and w/rs.
// SIDE 0 (g-update): struct = transpose (yx for xy, self for xx/yy), gathers ratio_f,
//                    writes rs_g/ratio_g with Y-side weights.
// SIDE 1 (f-update): struct = original, gathers ratio_g, writes rs_f/ratio_f (X-side w).
template <int SIDE>
__global__ void __launch_bounds__(THREADS) sparse_mv(
        const unsigned* __restrict__ slab, const unsigned* __restrict__ counts,
        const unsigned* __restrict__ rsl, const unsigned* __restrict__ sbase,
        const float* __restrict__ ratio_src, float* __restrict__ rs_dst,
        float* __restrict__ ratio_dst,
        const float* __restrict__ wx, const float* __restrict__ wy) {
    int w = (blockIdx.x * THREADS + threadIdx.x) >> 6;
    int lane = threadIdx.x & 63;
    int p = w >> 11, r = w & 2047;
    int s = (SIDE == 0) ? ((p < 8) ? 24 + p : p) : p;
    unsigned start = sbase[s] + rsl[s * PTS + r];
    unsigned cnt   = counts[s * PTS + r];
    const float* rsrc = ratio_src + (size_t)p * PTS;
    float acc = 0.0f;
    for (unsigned k = lane; k < cnt; k += 64) {
        unsigned e = slab[start + k];
        float L = f16bits_to_f32((unsigned short)(e & 0xffffu));
        acc = fmaf(__builtin_amdgcn_exp2f(L), rsrc[e >> 16], acc);
    }
    for (int off = 32; off; off >>= 1) acc += __shfl_down(acc, off, 64);
    if (lane == 0) {
        const float *wa, *wb;
        prob_w(p, wx, wy, &wa, &wb);
        float wrow = (SIDE == 0) ? wb[r] : wa[r];
        rs_dst[(size_t)p * PTS + r] = acc;
        ratio_dst[(size_t)p * PTS + r] = wrow / acc;
    }
}

// OT_p = -eps*ln2*( sum_i a_i log2 rs_f_i + sum_j b_j log2 rs_g_j )
__global__ void __launch_bounds__(THREADS) ot_reduce_sp(
        const float* __restrict__ wx, const float* __restrict__ wy,
        const float* __restrict__ rs_f, const float* __restrict__ rs_g,
        float* __restrict__ ot) {
    int p = blockIdx.x;
    const float *wa, *wb;
    prob_w(p, wx, wy, &wa, &wb);
    const float* rf = rs_f + (size_t)p * PTS;
    const float* rg = rs_g + (size_t)p * PTS;
    float acc = 0.0f;
    for (int i = threadIdx.x; i < PTS; i += THREADS)
        acc += wa[i] * __builtin_amdgcn_logf(rf[i]) + wb[i] * __builtin_amdgcn_logf(rg[i]);
    for (int off = 32; off; off >>= 1) acc += __shfl_down(acc, off, 64);
    __shared__ float red[THREADS / 64];
    if ((threadIdx.x & 63) == 0) red[threadIdx.x >> 6] = acc;
    __syncthreads();
    if (threadIdx.x == 0)
        ot[p] = -EPS_LN2 * (red[0] + red[1] + red[2] + red[3]);
}

__global__ void combine(const float* __restrict__ ot, float* __restrict__ out) {
    if (threadIdx.x == 0) {
        float s = 0.0f;
        for (int n = 0; n < NBATCH; ++n)
            s += ot[n] - 0.5f * (ot[8 + n] + ot[16 + n]);
        out[0] = s / (float)NBATCH;
    }
}

// ---------------- dense fallback (r3 path, passed @1600us) ----------------

#define MRD     2
#define ROWSPB  (THREADS * MRD)
#define RGD     (PTS / ROWSPB)

template <int JCv>
__global__ void __launch_bounds__(THREADS) init_partials(float* __restrict__ partA) {
    int i = blockIdx.x * THREADS + threadIdx.x;
    int p = i / PTS, r = i % PTS;
    float* base = partA + (size_t)p * JCv * PTS;
    base[r] = 1.0f;
    #pragma unroll
    for (int c = 1; c < JCv; ++c) base[c * PTS + r] = 0.0f;
}

__device__ __forceinline__ void prob_pts(int p,
        const float* x, const float* y, const float** Xp, const float** Yp) {
    int type = p >> 3, n = p & 7;
    *Xp = ((type <= 1) ? x : y) + (size_t)n * PTS * 4;
    *Yp = ((type == 0) ? y : ((type == 1) ? x : y)) + (size_t)n * PTS * 4;
}

template <int JCv>
__global__ void __launch_bounds__(THREADS) half_update(
        const float* __restrict__ x,  const float* __restrict__ y,
        const float* __restrict__ wx, const float* __restrict__ wy,
        const float* __restrict__ part_in, float* __restrict__ part_out, int side)
{
    constexpr int CHUNK = PTS / JCv;
    __shared__ float4 cpts[CHUNK];
    __shared__ float  clw[CHUNK];
    int b = blockIdx.x;
    int p = b / (RGD * JCv);
    int rem = b % (RGD * JCv);
    int rg = rem / JCv, jc = rem % JCv;
    const float *Xp, *Yp, *wa, *wb;
    prob_pts(p, x, y, &Xp, &Yp);
    prob_w(p, wx, wy, &wa, &wb);
    const float* rowPts = (side == 0) ? Yp : Xp;
    const float* colPts = (side == 0) ? Xp : Yp;
    const float* wcol   = (side == 0) ? wa : wb;
    const float* pin = part_in + (size_t)p * JCv * PTS;
    for (int k = threadIdx.x; k < CHUNK; k += THREADS) {
        int j = jc * CHUNK + k;
        float s = 0.0f;
        #pragma unroll
        for (int c = 0; c < JCv; ++c) s += pin[c * PTS + j];
        clw[k]  = __builtin_amdgcn_logf(wcol[j]) - __builtin_amdgcn_logf(s);
        cpts[k] = reinterpret_cast<const float4*>(colPts)[j];
    }
    __syncthreads();
    int r0 = rg * ROWSPB + threadIdx.x;
    int r1 = r0 + THREADS;
    float4 ra = reinterpret_cast<const float4*>(rowPts)[r0];
    float4 rb = reinterpret_cast<const float4*>(rowPts)[r1];
    float acc0 = 0.0f, acc1 = 0.0f;
    #pragma unroll 4
    for (int k = 0; k < CHUNK; ++k) {
        float4 q = cpts[k];
        float lw = clw[k];
        float d0 = ra.x*q.x, d1 = rb.x*q.x;
        d0 = fmaf(ra.y,q.y,d0);  d1 = fmaf(rb.y,q.y,d1);
        d0 = fmaf(ra.z,q.z,d0);  d1 = fmaf(rb.z,q.z,d1);
        d0 = fmaf(ra.w,q.w,d0);  d1 = fmaf(rb.w,q.w,d1);
        float t0 = fminf(fabsf(d0), CLIP), t1 = fminf(fabsf(d1), CLIP);
        float s0 = __builtin_amdgcn_sqrtf(1.0f - t0);
        float s1 = __builtin_amdgcn_sqrtf(1.0f - t1);
        float A0 = s0 * acos_poly(t0), A1 = s1 * acos_poly(t1);
        acc0 += __builtin_amdgcn_exp2f(fmaf(A0, EXP_SCALE, lw));
        acc1 += __builtin_amdgcn_exp2f(fmaf(A1, EXP_SCALE, lw));
    }
    float* pout = part_out + ((size_t)p * JCv + jc) * PTS;
    pout[r0] = acc0;
    pout[r1] = acc1;
}

template <int JCv>
__global__ void __launch_bounds__(THREADS) ot_reduce_d(
        const float* __restrict__ wx, const float* __restrict__ wy,
        const float* __restrict__ partA, const float* __restrict__ partB,
        float* __restrict__ ot)
{
    int p = blockIdx.x;
    const float *wa, *wb;
    prob_w(p, wx, wy, &wa, &wb);
    const float* pa = partA + (size_t)p * JCv * PTS;
    const float* pb = partB + (size_t)p * JCv * PTS;
    float acc = 0.0f;
    for (int i = threadIdx.x; i < PTS; i += THREADS) {
        float rsA = 0.0f, rsB = 0.0f;
        #pragma unroll
        for (int c = 0; c < JCv; ++c) { rsA += pa[c*PTS+i]; rsB += pb[c*PTS+i]; }
        acc += wa[i] * __builtin_amdgcn_logf(rsA) + wb[i] * __builtin_amdgcn_logf(rsB);
    }
    for (int off = 32; off; off >>= 1) acc += __shfl_down(acc, off, 64);
    __shared__ float red[THREADS / 64];
    if ((threadIdx.x & 63) == 0) red[threadIdx.x >> 6] = acc;
    __syncthreads();
    if (threadIdx.x == 0)
        ot[p] = -EPS_LN2 * (red[0] + red[1] + red[2] + red[3]);
}

template <int JCv>
static void run_dense(const float* x, const float* y, const float* wx, const float* wy,
                      float* out, void* d_ws, hipStream_t stream)
{
    float* partA = (float*)d_ws;
    float* partB = partA + (size_t)NPROB * JCv * PTS;
    float* ot    = partB + (size_t)NPROB * JCv * PTS;
    init_partials<JCv><<<NPROB * PTS / THREADS, THREADS, 0, stream>>>(partA);
    for (int it = 0; it < MAX_ITER; ++it) {
        half_update<JCv><<<NPROB * RGD * JCv, THREADS, 0, stream>>>(x, y, wx, wy, partA, partB, 0);
        half_update<JCv><<<NPROB * RGD * JCv, THREADS, 0, stream>>>(x, y, wx, wy, partB, partA, 1);
    }
    ot_reduce_d<JCv><<<NPROB, THREADS, 0, stream>>>(wx, wy, partA, partB, ot);
    combine<<<1, 64, 0, stream>>>(ot, out);
}

// ---------------- launcher ----------------

extern "C" void kernel_launch(void* const* d_in, const int* in_sizes, int n_in,
                              void* d_out, int out_size, void* d_ws, size_t ws_size,
                              hipStream_t stream)
{
    // setup_inputs dict order: y, w_y, x, w_x
    const float* y  = (const float*)d_in[0];
    const float* wy = (const float*)d_in[1];
    const float* x  = (const float*)d_in[2];
    const float* wx = (const float*)d_in[3];
    float* out = (float*)d_out;

    // sparse ws layout
    size_t off = 0;
    unsigned* slab   = (unsigned*)d_ws;          off += (size_t)CAP_ENTRIES * 4;
    unsigned* counts = (unsigned*)((char*)d_ws + off); off += (size_t)NSTRUCT * PTS * 4;
    unsigned* rsl    = (unsigned*)((char*)d_ws + off); off += (size_t)NSTRUCT * PTS * 4;
    unsigned* stotal = (unsigned*)((char*)d_ws + off); off += 64 * 4;
    unsigned* sbase  = (unsigned*)((char*)d_ws + off); off += 64 * 4;
    float* rs_f    = (float*)((char*)d_ws + off); off += (size_t)NPROB * PTS * 4;
    float* rs_g    = (float*)((char*)d_ws + off); off += (size_t)NPROB * PTS * 4;
    float* ratio_f = (float*)((char*)d_ws + off); off += (size_t)NPROB * PTS * 4;
    float* ratio_g = (float*)((char*)d_ws + off); off += (size_t)NPROB * PTS * 4;
    float* ot      = (float*)((char*)d_ws + off); off += 64 * 4;

    if (ws_size >= off) {
        int wave_blocks_s = NSTRUCT * PTS / 4;   // 1 wave per (struct,row), 4 waves/block
        int wave_blocks_p = NPROB * PTS / 4;     // 1 wave per (prob,row)
        init_state<<<NPROB * PTS / THREADS, THREADS, 0, stream>>>(wx, wy, rs_f, ratio_f);
        count_kernel<<<wave_blocks_s, THREADS, 0, stream>>>(x, y, counts);
        scan_kernel<<<NSTRUCT, THREADS, 0, stream>>>(counts, rsl, stotal);
        base_kernel<<<1, 64, 0, stream>>>(stotal, sbase);
        fill_kernel<<<wave_blocks_s, THREADS, 0, stream>>>(x, y, rsl, sbase, slab);
        for (int it = 0; it < MAX_ITER; ++it) {
            sparse_mv<0><<<wave_blocks_p, THREADS, 0, stream>>>(
                slab, counts, rsl, sbase, ratio_f, rs_g, ratio_g, wx, wy);
            sparse_mv<1><<<wave_blocks_p, THREADS, 0, stream>>>(
                slab, counts, rsl, sbase, ratio_g, rs_f, ratio_f, wx, wy);
        }
        ot_reduce_sp<<<NPROB, THREADS, 0, stream>>>(wx, wy, rs_f, rs_g, ot);
        combine<<<1, 64, 0, stream>>>(ot, out);
    } else {
        size_t need8 = ((size_t)2 * NPROB * 8 * PTS + NPROB) * sizeof(float);
        if (ws_size >= need8) run_dense<8>(x, y, wx, wy, out, d_ws, stream);
        else                  run_dense<4>(x, y, wx, wy, out, d_ws, stream);
    }
}

// Round 6
// 1008.390 us; speedup vs baseline: 2.4216x; 1.4360x over previous
//
#include <hip/hip_runtime.h>
#include <hip/hip_fp16.h>

#define PTS     2048
#define NBATCH  8
#define NPROB   24          // 8 xy + 8 xx + 8 yy
#define NSTRUCT 32          // 24 originals + 8 yx transposes (for xy side-0)
#define THREADS 256
#define MAX_ITER 20

// k(x,y) = exp(-2*acos(min(|x.y|,1-1e-7))/0.05) = 2^(EXP_SCALE * acos(t))
#define EXP_SCALE (-57.70780163555853f)   // -(2/0.05)*log2(e)
#define EPS_LN2   (0.034657359027997264f) // 0.05 * ln(2)
#define CLIP      (0.9999999f)

// Sparsity cutoff: keep entries with L > -44  (theta < 0.76246 rad)
#define T_CUT     (0.7231383f)
#define CAP_ENTRIES (28u*1024u*1024u)     // 28M entries (expect ~22.5M) = 112 MB

// acos(t) = sqrt(1-t)*poly(t), |err| <= 6.8e-5 on [0,1] (A&S 4.4.45 4-term)
__device__ __forceinline__ float acos_poly(float t) {
    float p = -0.0187292994f;
    p = fmaf(p, t,  0.0742610022f);
    p = fmaf(p, t, -0.2121143937f);
    p = fmaf(p, t,  1.5707287550f);
    return p;
}

__device__ __forceinline__ unsigned short f32_to_f16bits(float f) {
    __half h = __float2half(f);
    return *reinterpret_cast<unsigned short*>(&h);
}
__device__ __forceinline__ float f16bits_to_f32(unsigned short u) {
    __half h = *reinterpret_cast<__half*>(&u);
    return __half2float(h);
}

// problem p: type=p>>3 (0:xy 1:xx 2:yy), batch n=p&7.
__device__ __forceinline__ void prob_w(int p, const float* wx, const float* wy,
                                       const float** wa, const float** wb) {
    int type = p >> 3, n = p & 7;
    *wa = ((type <= 1) ? wx : wy) + (size_t)n * PTS;
    *wb = ((type == 0) ? wy : ((type == 1) ? wx : wy)) + (size_t)n * PTS;
}

// structure s: s<24 -> CSR of K_p; s in [24,32) -> CSR of K_{yx,n} (transpose for xy side-0)
__device__ __forceinline__ void struct_ptrs(int s,
        const float* x, const float* y, const float** rowP, const float** colP) {
    if (s < 24) {
        int type = s >> 3, n = s & 7;
        *rowP = ((type <= 1) ? x : y) + (size_t)n * PTS * 4;
        *colP = ((type == 0) ? y : ((type == 1) ? x : y)) + (size_t)n * PTS * 4;
    } else {
        int n = s - 24;
        *rowP = y + (size_t)n * PTS * 4;
        *colP = x + (size_t)n * PTS * 4;
    }
}

// ---------------- sparse-cache path ----------------

// rs_f = 1, ratio_f = a  (f = 0 start)
__global__ void __launch_bounds__(THREADS) init_state(
        const float* __restrict__ wx, const float* __restrict__ wy,
        float* __restrict__ rs_f, float* __restrict__ ratio_f) {
    int i = blockIdx.x * THREADS + threadIdx.x;   // over NPROB*PTS
    int p = i / PTS, r = i % PTS;
    const float *wa, *wb;
    prob_w(p, wx, wy, &wa, &wb);
    rs_f[i] = 1.0f;
    ratio_f[i] = wa[r];
}

// 4 rows per wave: count columns with t > T_CUT.
// block = 16 rows of one struct; grid = NSTRUCT * 128
__global__ void __launch_bounds__(THREADS) count_kernel(
        const float* __restrict__ x, const float* __restrict__ y,
        unsigned* __restrict__ counts) {
    int s  = blockIdx.x >> 7;
    int rb = blockIdx.x & 127;
    int wv = threadIdx.x >> 6, lane = threadIdx.x & 63;
    const float *rowP, *colP;
    struct_ptrs(s, x, y, &rowP, &colP);
    int r0 = rb * 16 + wv * 4;
    float4 rp[4];
    unsigned cnt[4] = {0,0,0,0};
    #pragma unroll
    for (int i = 0; i < 4; ++i) rp[i] = reinterpret_cast<const float4*>(rowP)[r0 + i];
    for (int base = 0; base < PTS; base += 64) {
        float4 q = reinterpret_cast<const float4*>(colP)[base + lane];
        #pragma unroll
        for (int i = 0; i < 4; ++i) {
            float d = rp[i].x*q.x;
            d = fmaf(rp[i].y,q.y,d); d = fmaf(rp[i].z,q.z,d); d = fmaf(rp[i].w,q.w,d);
            float t = fminf(fabsf(d), CLIP);
            cnt[i] += (unsigned)__popcll(__ballot(t > T_CUT));
        }
    }
    if (lane == 0) {
        #pragma unroll
        for (int i = 0; i < 4; ++i) counts[s * PTS + r0 + i] = cnt[i];
    }
}

// exclusive scan of 2048 counts per structure -> row_start_local + struct_total
__global__ void __launch_bounds__(THREADS) scan_kernel(
        const unsigned* __restrict__ counts, unsigned* __restrict__ rsl,
        unsigned* __restrict__ stotal) {
    int s = blockIdx.x, tid = threadIdx.x;
    const unsigned* c = counts + (size_t)s * PTS;
    unsigned v[8], sum = 0;
    #pragma unroll
    for (int q = 0; q < 8; ++q) { v[q] = c[tid*8+q]; sum += v[q]; }
    __shared__ unsigned ts[THREADS];
    ts[tid] = sum; __syncthreads();
    for (int off = 1; off < THREADS; off <<= 1) {
        unsigned add = (tid >= off) ? ts[tid-off] : 0u;
        __syncthreads();
        ts[tid] += add; __syncthreads();
    }
    unsigned run = (tid == 0) ? 0u : ts[tid-1];
    unsigned* out = rsl + (size_t)s * PTS;
    #pragma unroll
    for (int q = 0; q < 8; ++q) { out[tid*8+q] = run; run += v[q]; }
    if (tid == THREADS-1) stotal[s] = ts[THREADS-1];
}

__global__ void base_kernel(const unsigned* __restrict__ stotal,
                            unsigned* __restrict__ sbase) {
    if (threadIdx.x == 0) {
        unsigned run = 0;
        for (int s = 0; s < NSTRUCT; ++s) { sbase[s] = run; run += stotal[s]; }
    }
}

// ordered compacted fill, 4 rows per wave: entry = (col_idx<<16) | f16(L)
__global__ void __launch_bounds__(THREADS) fill_kernel(
        const float* __restrict__ x, const float* __restrict__ y,
        const unsigned* __restrict__ rsl, const unsigned* __restrict__ sbase,
        unsigned* __restrict__ slab) {
    int s  = blockIdx.x >> 7;
    int rb = blockIdx.x & 127;
    int wv = threadIdx.x >> 6, lane = threadIdx.x & 63;
    const float *rowP, *colP;
    struct_ptrs(s, x, y, &rowP, &colP);
    int r0 = rb * 16 + wv * 4;
    float4 rp[4];
    unsigned off[4];
    #pragma unroll
    for (int i = 0; i < 4; ++i) {
        rp[i]  = reinterpret_cast<const float4*>(rowP)[r0 + i];
        off[i] = sbase[s] + rsl[s * PTS + r0 + i];
    }
    unsigned long long lt_mask = (1ull << lane) - 1ull;   // bits [0, lane)
    for (int base = 0; base < PTS; base += 64) {
        int j = base + lane;
        float4 q = reinterpret_cast<const float4*>(colP)[j];
        #pragma unroll
        for (int i = 0; i < 4; ++i) {
            float d = rp[i].x*q.x;
            d = fmaf(rp[i].y,q.y,d); d = fmaf(rp[i].z,q.z,d); d = fmaf(rp[i].w,q.w,d);
            float t = fminf(fabsf(d), CLIP);
            bool pass = t > T_CUT;
            unsigned long long bal = __ballot(pass);
            if (pass) {
                float sr = __builtin_amdgcn_sqrtf(1.0f - t);
                float L  = EXP_SCALE * (sr * acos_poly(t));
                unsigned pos = off[i] + (unsigned)__popcll(bal & lt_mask);
                if (pos < CAP_ENTRIES)
                    slab[pos] = ((unsigned)j << 16) | f32_to_f16bits(L);
            }
            off[i] += (unsigned)__popcll(bal);
        }
    }
}

// block = 16 rows of one problem; ratio table staged in LDS (kills divergent-L1 gather).
// SIDE 0 (g-update): struct = transpose (yx for xy, self for xx/yy), gathers ratio_f,
//                    writes rs_g/ratio_g with Y-side weights.
// SIDE 1 (f-update): struct = original, gathers ratio_g, writes rs_f/ratio_f (X-side w).
template <int SIDE>
__global__ void __launch_bounds__(THREADS) sparse_mv(
        const unsigned* __restrict__ slab, const unsigned* __restrict__ counts,
        const unsigned* __restrict__ rsl, const unsigned* __restrict__ sbase,
        const float* __restrict__ ratio_src, float* __restrict__ rs_dst,
        float* __restrict__ ratio_dst,
        const float* __restrict__ wx, const float* __restrict__ wy) {
    __shared__ float lds_ratio[PTS];
    int p  = blockIdx.x >> 7;           // 128 row-blocks (16 rows) per problem
    int rb = blockIdx.x & 127;
    const float* rsrc = ratio_src + (size_t)p * PTS;
    for (int i = threadIdx.x; i < PTS/4; i += THREADS)
        reinterpret_cast<float4*>(lds_ratio)[i] = reinterpret_cast<const float4*>(rsrc)[i];
    __syncthreads();

    int wv = threadIdx.x >> 6, lane = threadIdx.x & 63;
    int s = (SIDE == 0) ? ((p < 8) ? 24 + p : p) : p;
    const float *wa, *wb;
    prob_w(p, wx, wy, &wa, &wb);

    for (int rr = 0; rr < 4; ++rr) {
        int r = rb * 16 + wv * 4 + rr;
        unsigned start = sbase[s] + rsl[s * PTS + r];
        unsigned cnt   = counts[s * PTS + r];
        float acc = 0.0f;
        unsigned k = lane;
        for (; k + 64 < cnt; k += 128) {      // 2 entries/lane/iter (2 loads in flight)
            unsigned e0 = slab[start + k];
            unsigned e1 = slab[start + k + 64];
            float l0 = f16bits_to_f32((unsigned short)(e0 & 0xffffu));
            float l1 = f16bits_to_f32((unsigned short)(e1 & 0xffffu));
            acc = fmaf(__builtin_amdgcn_exp2f(l0), lds_ratio[e0 >> 16], acc);
            acc = fmaf(__builtin_amdgcn_exp2f(l1), lds_ratio[e1 >> 16], acc);
        }
        if (k < cnt) {
            unsigned e = slab[start + k];
            float l = f16bits_to_f32((unsigned short)(e & 0xffffu));
            acc = fmaf(__builtin_amdgcn_exp2f(l), lds_ratio[e >> 16], acc);
        }
        for (int off = 32; off; off >>= 1) acc += __shfl_down(acc, off, 64);
        if (lane == 0) {
            float wrow = (SIDE == 0) ? wb[r] : wa[r];
            rs_dst[(size_t)p * PTS + r] = acc;
            ratio_dst[(size_t)p * PTS + r] = wrow / acc;
        }
    }
}

// OT_p = -eps*ln2*( sum_i a_i log2 rs_f_i + sum_j b_j log2 rs_g_j )
__global__ void __launch_bounds__(THREADS) ot_reduce_sp(
        const float* __restrict__ wx, const float* __restrict__ wy,
        const float* __restrict__ rs_f, const float* __restrict__ rs_g,
        float* __restrict__ ot) {
    int p = blockIdx.x;
    const float *wa, *wb;
    prob_w(p, wx, wy, &wa, &wb);
    const float* rf = rs_f + (size_t)p * PTS;
    const float* rg = rs_g + (size_t)p * PTS;
    float acc = 0.0f;
    for (int i = threadIdx.x; i < PTS; i += THREADS)
        acc += wa[i] * __builtin_amdgcn_logf(rf[i]) + wb[i] * __builtin_amdgcn_logf(rg[i]);
    for (int off = 32; off; off >>= 1) acc += __shfl_down(acc, off, 64);
    __shared__ float red[THREADS / 64];
    if ((threadIdx.x & 63) == 0) red[threadIdx.x >> 6] = acc;
    __syncthreads();
    if (threadIdx.x == 0)
        ot[p] = -EPS_LN2 * (red[0] + red[1] + red[2] + red[3]);
}

__global__ void combine(const float* __restrict__ ot, float* __restrict__ out) {
    if (threadIdx.x == 0) {
        float s = 0.0f;
        for (int n = 0; n < NBATCH; ++n)
            s += ot[n] - 0.5f * (ot[8 + n] + ot[16 + n]);
        out[0] = s / (float)NBATCH;
    }
}

// ---------------- dense fallback (r3 path, passed @1600us) ----------------

#define MRD     2
#define ROWSPB  (THREADS * MRD)
#define RGD     (PTS / ROWSPB)

template <int JCv>
__global__ void __launch_bounds__(THREADS) init_partials(float* __restrict__ partA) {
    int i = blockIdx.x * THREADS + threadIdx.x;
    int p = i / PTS, r = i % PTS;
    float* base = partA + (size_t)p * JCv * PTS;
    base[r] = 1.0f;
    #pragma unroll
    for (int c = 1; c < JCv; ++c) base[c * PTS + r] = 0.0f;
}

__device__ __forceinline__ void prob_pts(int p,
        const float* x, const float* y, const float** Xp, const float** Yp) {
    int type = p >> 3, n = p & 7;
    *Xp = ((type <= 1) ? x : y) + (size_t)n * PTS * 4;
    *Yp = ((type == 0) ? y : ((type == 1) ? x : y)) + (size_t)n * PTS * 4;
}

template <int JCv>
__global__ void __launch_bounds__(THREADS) half_update(
        const float* __restrict__ x,  const float* __restrict__ y,
        const float* __restrict__ wx, const float* __restrict__ wy,
        const float* __restrict__ part_in, float* __restrict__ part_out, int side)
{
    constexpr int CHUNK = PTS / JCv;
    __shared__ float4 cpts[CHUNK];
    __shared__ float  clw[CHUNK];
    int b = blockIdx.x;
    int p = b / (RGD * JCv);
    int rem = b % (RGD * JCv);
    int rg = rem / JCv, jc = rem % JCv;
    const float *Xp, *Yp, *wa, *wb;
    prob_pts(p, x, y, &Xp, &Yp);
    prob_w(p, wx, wy, &wa, &wb);
    const float* rowPts = (side == 0) ? Yp : Xp;
    const float* colPts = (side == 0) ? Xp : Yp;
    const float* wcol   = (side == 0) ? wa : wb;
    const float* pin = part_in + (size_t)p * JCv * PTS;
    for (int k = threadIdx.x; k < CHUNK; k += THREADS) {
        int j = jc * CHUNK + k;
        float s = 0.0f;
        #pragma unroll
        for (int c = 0; c < JCv; ++c) s += pin[c * PTS + j];
        clw[k]  = __builtin_amdgcn_logf(wcol[j]) - __builtin_amdgcn_logf(s);
        cpts[k] = reinterpret_cast<const float4*>(colPts)[j];
    }
    __syncthreads();
    int r0 = rg * ROWSPB + threadIdx.x;
    int r1 = r0 + THREADS;
    float4 ra = reinterpret_cast<const float4*>(rowPts)[r0];
    float4 rb = reinterpret_cast<const float4*>(rowPts)[r1];
    float acc0 = 0.0f, acc1 = 0.0f;
    #pragma unroll 4
    for (int k = 0; k < CHUNK; ++k) {
        float4 q = cpts[k];
        float lw = clw[k];
        float d0 = ra.x*q.x, d1 = rb.x*q.x;
        d0 = fmaf(ra.y,q.y,d0);  d1 = fmaf(rb.y,q.y,d1);
        d0 = fmaf(ra.z,q.z,d0);  d1 = fmaf(rb.z,q.z,d1);
        d0 = fmaf(ra.w,q.w,d0);  d1 = fmaf(rb.w,q.w,d1);
        float t0 = fminf(fabsf(d0), CLIP), t1 = fminf(fabsf(d1), CLIP);
        float s0 = __builtin_amdgcn_sqrtf(1.0f - t0);
        float s1 = __builtin_amdgcn_sqrtf(1.0f - t1);
        float A0 = s0 * acos_poly(t0), A1 = s1 * acos_poly(t1);
        acc0 += __builtin_amdgcn_exp2f(fmaf(A0, EXP_SCALE, lw));
        acc1 += __builtin_amdgcn_exp2f(fmaf(A1, EXP_SCALE, lw));
    }
    float* pout = part_out + ((size_t)p * JCv + jc) * PTS;
    pout[r0] = acc0;
    pout[r1] = acc1;
}

template <int JCv>
__global__ void __launch_bounds__(THREADS) ot_reduce_d(
        const float* __restrict__ wx, const float* __restrict__ wy,
        const float* __restrict__ partA, const float* __restrict__ partB,
        float* __restrict__ ot)
{
    int p = blockIdx.x;
    const float *wa, *wb;
    prob_w(p, wx, wy, &wa, &wb);
    const float* pa = partA + (size_t)p * JCv * PTS;
    const float* pb = partB + (size_t)p * JCv * PTS;
    float acc = 0.0f;
    for (int i = threadIdx.x; i < PTS; i += THREADS) {
        float rsA = 0.0f, rsB = 0.0f;
        #pragma unroll
        for (int c = 0; c < JCv; ++c) { rsA += pa[c*PTS+i]; rsB += pb[c*PTS+i]; }
        acc += wa[i] * __builtin_amdgcn_logf(rsA) + wb[i] * __builtin_amdgcn_logf(rsB);
    }
    for (int off = 32; off; off >>= 1) acc += __shfl_down(acc, off, 64);
    __shared__ float red[THREADS / 64];
    if ((threadIdx.x & 63) == 0) red[threadIdx.x >> 6] = acc;
    __syncthreads();
    if (threadIdx.x == 0)
        ot[p] = -EPS_LN2 * (red[0] + red[1] + red[2] + red[3]);
}

template <int JCv>
static void run_dense(const float* x, const float* y, const float* wx, const float* wy,
                      float* out, void* d_ws, hipStream_t stream)
{
    float* partA = (float*)d_ws;
    float* partB = partA + (size_t)NPROB * JCv * PTS;
    float* ot    = partB + (size_t)NPROB * JCv * PTS;
    init_partials<JCv><<<NPROB * PTS / THREADS, THREADS, 0, stream>>>(partA);
    for (int it = 0; it < MAX_ITER; ++it) {
        half_update<JCv><<<NPROB * RGD * JCv, THREADS, 0, stream>>>(x, y, wx, wy, partA, partB, 0);
        half_update<JCv><<<NPROB * RGD * JCv, THREADS, 0, stream>>>(x, y, wx, wy, partB, partA, 1);
    }
    ot_reduce_d<JCv><<<NPROB, THREADS, 0, stream>>>(wx, wy, partA, partB, ot);
    combine<<<1, 64, 0, stream>>>(ot, out);
}

// ---------------- launcher ----------------

extern "C" void kernel_launch(void* const* d_in, const int* in_sizes, int n_in,
                              void* d_out, int out_size, void* d_ws, size_t ws_size,
                              hipStream_t stream)
{
    // setup_inputs dict order: y, w_y, x, w_x
    const float* y  = (const float*)d_in[0];
    const float* wy = (const float*)d_in[1];
    const float* x  = (const float*)d_in[2];
    const float* wx = (const float*)d_in[3];
    float* out = (float*)d_out;

    // sparse ws layout
    size_t off = 0;
    unsigned* slab   = (unsigned*)d_ws;          off += (size_t)CAP_ENTRIES * 4;
    unsigned* counts = (unsigned*)((char*)d_ws + off); off += (size_t)NSTRUCT * PTS * 4;
    unsigned* rsl    = (unsigned*)((char*)d_ws + off); off += (size_t)NSTRUCT * PTS * 4;
    unsigned* stotal = (unsigned*)((char*)d_ws + off); off += 64 * 4;
    unsigned* sbase  = (unsigned*)((char*)d_ws + off); off += 64 * 4;
    float* rs_f    = (float*)((char*)d_ws + off); off += (size_t)NPROB * PTS * 4;
    float* rs_g    = (float*)((char*)d_ws + off); off += (size_t)NPROB * PTS * 4;
    float* ratio_f = (float*)((char*)d_ws + off); off += (size_t)NPROB * PTS * 4;
    float* ratio_g = (float*)((char*)d_ws + off); off += (size_t)NPROB * PTS * 4;
    float* ot      = (float*)((char*)d_ws + off); off += 64 * 4;

    if (ws_size >= off) {
        int blocks_s = NSTRUCT * (PTS / 16);   // 16 rows/block (4 rows/wave)
        int blocks_p = NPROB * (PTS / 16);     // 16 rows/block
        init_state<<<NPROB * PTS / THREADS, THREADS, 0, stream>>>(wx, wy, rs_f, ratio_f);
        count_kernel<<<blocks_s, THREADS, 0, stream>>>(x, y, counts);
        scan_kernel<<<NSTRUCT, THREADS, 0, stream>>>(counts, rsl, stotal);
        base_kernel<<<1, 64, 0, stream>>>(stotal, sbase);
        fill_kernel<<<blocks_s, THREADS, 0, stream>>>(x, y, rsl, sbase, slab);
        for (int it = 0; it < MAX_ITER; ++it) {
            sparse_mv<0><<<blocks_p, THREADS, 0, stream>>>(
                slab, counts, rsl, sbase, ratio_f, rs_g, ratio_g, wx, wy);
            sparse_mv<1><<<blocks_p, THREADS, 0, stream>>>(
                slab, counts, rsl, sbase, ratio_g, rs_f, ratio_f, wx, wy);
        }
        ot_reduce_sp<<<NPROB, THREADS, 0, stream>>>(wx, wy, rs_f, rs_g, ot);
        combine<<<1, 64, 0, stream>>>(ot, out);
    } else {
        size_t need8 = ((size_t)2 * NPROB * 8 * PTS + NPROB) * sizeof(float);
        if (ws_size >= need8) run_dense<8>(x, y, wx, wy, out, d_ws, stream);
        else                  run_dense<4>(x, y, wx, wy, out, d_ws, stream);
    }
}

// Round 7
// 760.330 us; speedup vs baseline: 3.2116x; 1.3263x over previous
//
#include <hip/hip_runtime.h>
#include <hip/hip_fp16.h>

#define PTS     2048
#define NBATCH  8
#define NPROB   24          // 8 xy + 8 xx + 8 yy
#define NSTRUCT 32          // 24 originals + 8 yx transposes (for xy side-0)
#define THREADS 256
#define MAX_ITER 20

// k(x,y) = exp(-2*acos(min(|x.y|,1-1e-7))/0.05) = 2^(EXP_SCALE * acos(t))
#define EXP_SCALE (-57.70780163555853f)   // -(2/0.05)*log2(e)
#define EPS_LN2   (0.034657359027997264f) // 0.05 * ln(2)
#define CLIP      (0.9999999f)

// Sparsity cutoff: keep entries with L > -40  (theta < 40/57.7078 = 0.69315 rad)
// t > cos(0.69315) = 0.769239. Density ~12.8%. Worst-isolated-row bound:
// culled/kept ~ 2048 * 2^(-40+14.4) * e^4 ~ 2.4e-3 -> df ~ 1.2e-4 << 4e-3 thr.
#define T_CUT     (0.769239f)
#define CAP_ENTRIES (28u*1024u*1024u)     // 28M entries (expect ~17M) = 112 MB

// acos(t) = sqrt(1-t)*poly(t), |err| <= 6.8e-5 on [0,1] (A&S 4.4.45 4-term)
__device__ __forceinline__ float acos_poly(float t) {
    float p = -0.0187292994f;
    p = fmaf(p, t,  0.0742610022f);
    p = fmaf(p, t, -0.2121143937f);
    p = fmaf(p, t,  1.5707287550f);
    return p;
}

__device__ __forceinline__ unsigned short f32_to_f16bits(float f) {
    __half h = __float2half(f);
    return *reinterpret_cast<unsigned short*>(&h);
}
__device__ __forceinline__ float f16bits_to_f32(unsigned short u) {
    __half h = *reinterpret_cast<__half*>(&u);
    return __half2float(h);
}

// problem p: type=p>>3 (0:xy 1:xx 2:yy), batch n=p&7.
__device__ __forceinline__ void prob_w(int p, const float* wx, const float* wy,
                                       const float** wa, const float** wb) {
    int type = p >> 3, n = p & 7;
    *wa = ((type <= 1) ? wx : wy) + (size_t)n * PTS;
    *wb = ((type == 0) ? wy : ((type == 1) ? wx : wy)) + (size_t)n * PTS;
}

// structure s: s<24 -> CSR of K_p; s in [24,32) -> CSR of K_{yx,n} (transpose for xy side-0)
__device__ __forceinline__ void struct_ptrs(int s,
        const float* x, const float* y, const float** rowP, const float** colP) {
    if (s < 24) {
        int type = s >> 3, n = s & 7;
        *rowP = ((type <= 1) ? x : y) + (size_t)n * PTS * 4;
        *colP = ((type == 0) ? y : ((type == 1) ? x : y)) + (size_t)n * PTS * 4;
    } else {
        int n = s - 24;
        *rowP = y + (size_t)n * PTS * 4;
        *colP = x + (size_t)n * PTS * 4;
    }
}

// ---------------- sparse-cache path ----------------

// rs_f = 1, ratio_f = a  (f = 0 start)
__global__ void __launch_bounds__(THREADS) init_state(
        const float* __restrict__ wx, const float* __restrict__ wy,
        float* __restrict__ rs_f, float* __restrict__ ratio_f) {
    int i = blockIdx.x * THREADS + threadIdx.x;   // over NPROB*PTS
    int p = i / PTS, r = i % PTS;
    const float *wa, *wb;
    prob_w(p, wx, wy, &wa, &wb);
    rs_f[i] = 1.0f;
    ratio_f[i] = wa[r];
}

// 4 rows per wave: count columns with t > T_CUT.
// block = 16 rows of one struct; grid = NSTRUCT * 128
__global__ void __launch_bounds__(THREADS) count_kernel(
        const float* __restrict__ x, const float* __restrict__ y,
        unsigned* __restrict__ counts) {
    int s  = blockIdx.x >> 7;
    int rb = blockIdx.x & 127;
    int wv = threadIdx.x >> 6, lane = threadIdx.x & 63;
    const float *rowP, *colP;
    struct_ptrs(s, x, y, &rowP, &colP);
    int r0 = rb * 16 + wv * 4;
    float4 rp[4];
    unsigned cnt[4] = {0,0,0,0};
    #pragma unroll
    for (int i = 0; i < 4; ++i) rp[i] = reinterpret_cast<const float4*>(rowP)[r0 + i];
    for (int base = 0; base < PTS; base += 64) {
        float4 q = reinterpret_cast<const float4*>(colP)[base + lane];
        #pragma unroll
        for (int i = 0; i < 4; ++i) {
            float d = rp[i].x*q.x;
            d = fmaf(rp[i].y,q.y,d); d = fmaf(rp[i].z,q.z,d); d = fmaf(rp[i].w,q.w,d);
            float t = fminf(fabsf(d), CLIP);
            cnt[i] += (unsigned)__popcll(__ballot(t > T_CUT));
        }
    }
    if (lane == 0) {
        #pragma unroll
        for (int i = 0; i < 4; ++i) counts[s * PTS + r0 + i] = cnt[i];
    }
}

// exclusive scan of 2048 counts per structure -> row_start_local + struct_total
__global__ void __launch_bounds__(THREADS) scan_kernel(
        const unsigned* __restrict__ counts, unsigned* __restrict__ rsl,
        unsigned* __restrict__ stotal) {
    int s = blockIdx.x, tid = threadIdx.x;
    const unsigned* c = counts + (size_t)s * PTS;
    unsigned v[8], sum = 0;
    #pragma unroll
    for (int q = 0; q < 8; ++q) { v[q] = c[tid*8+q]; sum += v[q]; }
    __shared__ unsigned ts[THREADS];
    ts[tid] = sum; __syncthreads();
    for (int off = 1; off < THREADS; off <<= 1) {
        unsigned add = (tid >= off) ? ts[tid-off] : 0u;
        __syncthreads();
        ts[tid] += add; __syncthreads();
    }
    unsigned run = (tid == 0) ? 0u : ts[tid-1];
    unsigned* out = rsl + (size_t)s * PTS;
    #pragma unroll
    for (int q = 0; q < 8; ++q) { out[tid*8+q] = run; run += v[q]; }
    if (tid == THREADS-1) stotal[s] = ts[THREADS-1];
}

__global__ void base_kernel(const unsigned* __restrict__ stotal,
                            unsigned* __restrict__ sbase) {
    if (threadIdx.x == 0) {
        unsigned run = 0;
        for (int s = 0; s < NSTRUCT; ++s) { sbase[s] = run; run += stotal[s]; }
    }
}

// ordered compacted fill, 4 rows per wave: entry = (col_idx<<16) | f16(L)
__global__ void __launch_bounds__(THREADS) fill_kernel(
        const float* __restrict__ x, const float* __restrict__ y,
        const unsigned* __restrict__ rsl, const unsigned* __restrict__ sbase,
        unsigned* __restrict__ slab) {
    int s  = blockIdx.x >> 7;
    int rb = blockIdx.x & 127;
    int wv = threadIdx.x >> 6, lane = threadIdx.x & 63;
    const float *rowP, *colP;
    struct_ptrs(s, x, y, &rowP, &colP);
    int r0 = rb * 16 + wv * 4;
    float4 rp[4];
    unsigned off[4];
    #pragma unroll
    for (int i = 0; i < 4; ++i) {
        rp[i]  = reinterpret_cast<const float4*>(rowP)[r0 + i];
        off[i] = sbase[s] + rsl[s * PTS + r0 + i];
    }
    unsigned long long lt_mask = (1ull << lane) - 1ull;   // bits [0, lane)
    for (int base = 0; base < PTS; base += 64) {
        int j = base + lane;
        float4 q = reinterpret_cast<const float4*>(colP)[j];
        #pragma unroll
        for (int i = 0; i < 4; ++i) {
            float d = rp[i].x*q.x;
            d = fmaf(rp[i].y,q.y,d); d = fmaf(rp[i].z,q.z,d); d = fmaf(rp[i].w,q.w,d);
            float t = fminf(fabsf(d), CLIP);
            bool pass = t > T_CUT;
            unsigned long long bal = __ballot(pass);
            if (pass) {
                float sr = __builtin_amdgcn_sqrtf(1.0f - t);
                float L  = EXP_SCALE * (sr * acos_poly(t));
                unsigned pos = off[i] + (unsigned)__popcll(bal & lt_mask);
                if (pos < CAP_ENTRIES)
                    slab[pos] = ((unsigned)j << 16) | f32_to_f16bits(L);
            }
            off[i] += (unsigned)__popcll(bal);
        }
    }
}

// block = 16 rows of one problem; ratio table staged in LDS.
// Per wave: 4 rows, unroll-4 entry loop (4 loads in flight), deferred
// interleaved shfl reduction (4 independent chains hide bpermute latency).
template <int SIDE>
__global__ void __launch_bounds__(THREADS) sparse_mv(
        const unsigned* __restrict__ slab, const unsigned* __restrict__ counts,
        const unsigned* __restrict__ rsl, const unsigned* __restrict__ sbase,
        const float* __restrict__ ratio_src, float* __restrict__ rs_dst,
        float* __restrict__ ratio_dst,
        const float* __restrict__ wx, const float* __restrict__ wy) {
    __shared__ float lds_ratio[PTS];
    int p  = blockIdx.x >> 7;           // 128 row-blocks (16 rows) per problem
    int rb = blockIdx.x & 127;
    const float* rsrc = ratio_src + (size_t)p * PTS;
    for (int i = threadIdx.x; i < PTS/4; i += THREADS)
        reinterpret_cast<float4*>(lds_ratio)[i] = reinterpret_cast<const float4*>(rsrc)[i];
    __syncthreads();

    int wv = threadIdx.x >> 6, lane = threadIdx.x & 63;
    int s = (SIDE == 0) ? ((p < 8) ? 24 + p : p) : p;
    int r0 = rb * 16 + wv * 4;

    unsigned start[4], cnt[4];
    #pragma unroll
    for (int i = 0; i < 4; ++i) {           // prefetch row descriptors together
        start[i] = sbase[s] + rsl[s * PTS + r0 + i];
        cnt[i]   = counts[s * PTS + r0 + i];
    }

    float acc[4];
    #pragma unroll
    for (int i = 0; i < 4; ++i) {
        float a = 0.0f;
        unsigned st = start[i], cn = cnt[i];
        unsigned k = lane;
        for (; k + 192 < cn; k += 256) {    // 4 entries/lane in flight
            unsigned e0 = slab[st + k];
            unsigned e1 = slab[st + k + 64];
            unsigned e2 = slab[st + k + 128];
            unsigned e3 = slab[st + k + 192];
            a = fmaf(__builtin_amdgcn_exp2f(f16bits_to_f32((unsigned short)(e0 & 0xffffu))), lds_ratio[e0 >> 16], a);
            a = fmaf(__builtin_amdgcn_exp2f(f16bits_to_f32((unsigned short)(e1 & 0xffffu))), lds_ratio[e1 >> 16], a);
            a = fmaf(__builtin_amdgcn_exp2f(f16bits_to_f32((unsigned short)(e2 & 0xffffu))), lds_ratio[e2 >> 16], a);
            a = fmaf(__builtin_amdgcn_exp2f(f16bits_to_f32((unsigned short)(e3 & 0xffffu))), lds_ratio[e3 >> 16], a);
        }
        for (; k < cn; k += 64) {
            unsigned e = slab[st + k];
            a = fmaf(__builtin_amdgcn_exp2f(f16bits_to_f32((unsigned short)(e & 0xffffu))), lds_ratio[e >> 16], a);
        }
        acc[i] = a;
    }

    #pragma unroll
    for (int off = 32; off; off >>= 1) {    // 4 interleaved reduction chains
        acc[0] += __shfl_down(acc[0], off, 64);
        acc[1] += __shfl_down(acc[1], off, 64);
        acc[2] += __shfl_down(acc[2], off, 64);
        acc[3] += __shfl_down(acc[3], off, 64);
    }
    if (lane == 0) {
        const float *wa, *wb;
        prob_w(p, wx, wy, &wa, &wb);
        #pragma unroll
        for (int i = 0; i < 4; ++i) {
            int r = r0 + i;
            float wrow = (SIDE == 0) ? wb[r] : wa[r];
            rs_dst[(size_t)p * PTS + r] = acc[i];
            ratio_dst[(size_t)p * PTS + r] = wrow / acc[i];
        }
    }
}

// OT_p = -eps*ln2*( sum_i a_i log2 rs_f_i + sum_j b_j log2 rs_g_j )
__global__ void __launch_bounds__(THREADS) ot_reduce_sp(
        const float* __restrict__ wx, const float* __restrict__ wy,
        const float* __restrict__ rs_f, const float* __restrict__ rs_g,
        float* __restrict__ ot) {
    int p = blockIdx.x;
    const float *wa, *wb;
    prob_w(p, wx, wy, &wa, &wb);
    const float* rf = rs_f + (size_t)p * PTS;
    const float* rg = rs_g + (size_t)p * PTS;
    float acc = 0.0f;
    for (int i = threadIdx.x; i < PTS; i += THREADS)
        acc += wa[i] * __builtin_amdgcn_logf(rf[i]) + wb[i] * __builtin_amdgcn_logf(rg[i]);
    for (int off = 32; off; off >>= 1) acc += __shfl_down(acc, off, 64);
    __shared__ float red[THREADS / 64];
    if ((threadIdx.x & 63) == 0) red[threadIdx.x >> 6] = acc;
    __syncthreads();
    if (threadIdx.x == 0)
        ot[p] = -EPS_LN2 * (red[0] + red[1] + red[2] + red[3]);
}

__global__ void combine(const float* __restrict__ ot, float* __restrict__ out) {
    if (threadIdx.x == 0) {
        float s = 0.0f;
        for (int n = 0; n < NBATCH; ++n)
            s += ot[n] - 0.5f * (ot[8 + n] + ot[16 + n]);
        out[0] = s / (float)NBATCH;
    }
}

// ---------------- dense fallback (r3 path, passed @1600us) ----------------

#define MRD     2
#define ROWSPB  (THREADS * MRD)
#define RGD     (PTS / ROWSPB)

template <int JCv>
__global__ void __launch_bounds__(THREADS) init_partials(float* __restrict__ partA) {
    int i = blockIdx.x * THREADS + threadIdx.x;
    int p = i / PTS, r = i % PTS;
    float* base = partA + (size_t)p * JCv * PTS;
    base[r] = 1.0f;
    #pragma unroll
    for (int c = 1; c < JCv; ++c) base[c * PTS + r] = 0.0f;
}

__device__ __forceinline__ void prob_pts(int p,
        const float* x, const float* y, const float** Xp, const float** Yp) {
    int type = p >> 3, n = p & 7;
    *Xp = ((type <= 1) ? x : y) + (size_t)n * PTS * 4;
    *Yp = ((type == 0) ? y : ((type == 1) ? x : y)) + (size_t)n * PTS * 4;
}

template <int JCv>
__global__ void __launch_bounds__(THREADS) half_update(
        const float* __restrict__ x,  const float* __restrict__ y,
        const float* __restrict__ wx, const float* __restrict__ wy,
        const float* __restrict__ part_in, float* __restrict__ part_out, int side)
{
    constexpr int CHUNK = PTS / JCv;
    __shared__ float4 cpts[CHUNK];
    __shared__ float  clw[CHUNK];
    int b = blockIdx.x;
    int p = b / (RGD * JCv);
    int rem = b % (RGD * JCv);
    int rg = rem / JCv, jc = rem % JCv;
    const float *Xp, *Yp, *wa, *wb;
    prob_pts(p, x, y, &Xp, &Yp);
    prob_w(p, wx, wy, &wa, &wb);
    const float* rowPts = (side == 0) ? Yp : Xp;
    const float* colPts = (side == 0) ? Xp : Yp;
    const float* wcol   = (side == 0) ? wa : wb;
    const float* pin = part_in + (size_t)p * JCv * PTS;
    for (int k = threadIdx.x; k < CHUNK; k += THREADS) {
        int j = jc * CHUNK + k;
        float s = 0.0f;
        #pragma unroll
        for (int c = 0; c < JCv; ++c) s += pin[c * PTS + j];
        clw[k]  = __builtin_amdgcn_logf(wcol[j]) - __builtin_amdgcn_logf(s);
        cpts[k] = reinterpret_cast<const float4*>(colPts)[j];
    }
    __syncthreads();
    int r0 = rg * ROWSPB + threadIdx.x;
    int r1 = r0 + THREADS;
    float4 ra = reinterpret_cast<const float4*>(rowPts)[r0];
    float4 rb = reinterpret_cast<const float4*>(rowPts)[r1];
    float acc0 = 0.0f, acc1 = 0.0f;
    #pragma unroll 4
    for (int k = 0; k < CHUNK; ++k) {
        float4 q = cpts[k];
        float lw = clw[k];
        float d0 = ra.x*q.x, d1 = rb.x*q.x;
        d0 = fmaf(ra.y,q.y,d0);  d1 = fmaf(rb.y,q.y,d1);
        d0 = fmaf(ra.z,q.z,d0);  d1 = fmaf(rb.z,q.z,d1);
        d0 = fmaf(ra.w,q.w,d0);  d1 = fmaf(rb.w,q.w,d1);
        float t0 = fminf(fabsf(d0), CLIP), t1 = fminf(fabsf(d1), CLIP);
        float s0 = __builtin_amdgcn_sqrtf(1.0f - t0);
        float s1 = __builtin_amdgcn_sqrtf(1.0f - t1);
        float A0 = s0 * acos_poly(t0), A1 = s1 * acos_poly(t1);
        acc0 += __builtin_amdgcn_exp2f(fmaf(A0, EXP_SCALE, lw));
        acc1 += __builtin_amdgcn_exp2f(fmaf(A1, EXP_SCALE, lw));
    }
    float* pout = part_out + ((size_t)p * JCv + jc) * PTS;
    pout[r0] = acc0;
    pout[r1] = acc1;
}

template <int JCv>
__global__ void __launch_bounds__(THREADS) ot_reduce_d(
        const float* __restrict__ wx, const float* __restrict__ wy,
        const float* __restrict__ partA, const float* __restrict__ partB,
        float* __restrict__ ot)
{
    int p = blockIdx.x;
    const float *wa, *wb;
    prob_w(p, wx, wy, &wa, &wb);
    const float* pa = partA + (size_t)p * JCv * PTS;
    const float* pb = partB + (size_t)p * JCv * PTS;
    float acc = 0.0f;
    for (int i = threadIdx.x; i < PTS; i += THREADS) {
        float rsA = 0.0f, rsB = 0.0f;
        #pragma unroll
        for (int c = 0; c < JCv; ++c) { rsA += pa[c*PTS+i]; rsB += pb[c*PTS+i]; }
        acc += wa[i] * __builtin_amdgcn_logf(rsA) + wb[i] * __builtin_amdgcn_logf(rsB);
    }
    for (int off = 32; off; off >>= 1) acc += __shfl_down(acc, off, 64);
    __shared__ float red[THREADS / 64];
    if ((threadIdx.x & 63) == 0) red[threadIdx.x >> 6] = acc;
    __syncthreads();
    if (threadIdx.x == 0)
        ot[p] = -EPS_LN2 * (red[0] + red[1] + red[2] + red[3]);
}

template <int JCv>
static void run_dense(const float* x, const float* y, const float* wx, const float* wy,
                      float* out, void* d_ws, hipStream_t stream)
{
    float* partA = (float*)d_ws;
    float* partB = partA + (size_t)NPROB * JCv * PTS;
    float* ot    = partB + (size_t)NPROB * JCv * PTS;
    init_partials<JCv><<<NPROB * PTS / THREADS, THREADS, 0, stream>>>(partA);
    for (int it = 0; it < MAX_ITER; ++it) {
        half_update<JCv><<<NPROB * RGD * JCv, THREADS, 0, stream>>>(x, y, wx, wy, partA, partB, 0);
        half_update<JCv><<<NPROB * RGD * JCv, THREADS, 0, stream>>>(x, y, wx, wy, partB, partA, 1);
    }
    ot_reduce_d<JCv><<<NPROB, THREADS, 0, stream>>>(wx, wy, partA, partB, ot);
    combine<<<1, 64, 0, stream>>>(ot, out);
}

// ---------------- launcher ----------------

extern "C" void kernel_launch(void* const* d_in, const int* in_sizes, int n_in,
                              void* d_out, int out_size, void* d_ws, size_t ws_size,
                              hipStream_t stream)
{
    // setup_inputs dict order: y, w_y, x, w_x
    const float* y  = (const float*)d_in[0];
    const float* wy = (const float*)d_in[1];
    const float* x  = (const float*)d_in[2];
    const float* wx = (const float*)d_in[3];
    float* out = (float*)d_out;

    // sparse ws layout
    size_t off = 0;
    unsigned* slab   = (unsigned*)d_ws;          off += (size_t)CAP_ENTRIES * 4;
    unsigned* counts = (unsigned*)((char*)d_ws + off); off += (size_t)NSTRUCT * PTS * 4;
    unsigned* rsl    = (unsigned*)((char*)d_ws + off); off += (size_t)NSTRUCT * PTS * 4;
    unsigned* stotal = (unsigned*)((char*)d_ws + off); off += 64 * 4;
    unsigned* sbase  = (unsigned*)((char*)d_ws + off); off += 64 * 4;
    float* rs_f    = (float*)((char*)d_ws + off); off += (size_t)NPROB * PTS * 4;
    float* rs_g    = (float*)((char*)d_ws + off); off += (size_t)NPROB * PTS * 4;
    float* ratio_f = (float*)((char*)d_ws + off); off += (size_t)NPROB * PTS * 4;
    float* ratio_g = (float*)((char*)d_ws + off); off += (size_t)NPROB * PTS * 4;
    float* ot      = (float*)((char*)d_ws + off); off += 64 * 4;

    if (ws_size >= off) {
        int blocks_s = NSTRUCT * (PTS / 16);   // 16 rows/block (4 rows/wave)
        int blocks_p = NPROB * (PTS / 16);     // 16 rows/block
        init_state<<<NPROB * PTS / THREADS, THREADS, 0, stream>>>(wx, wy, rs_f, ratio_f);
        count_kernel<<<blocks_s, THREADS, 0, stream>>>(x, y, counts);
        scan_kernel<<<NSTRUCT, THREADS, 0, stream>>>(counts, rsl, stotal);
        base_kernel<<<1, 64, 0, stream>>>(stotal, sbase);
        fill_kernel<<<blocks_s, THREADS, 0, stream>>>(x, y, rsl, sbase, slab);
        for (int it = 0; it < MAX_ITER; ++it) {
            sparse_mv<0><<<blocks_p, THREADS, 0, stream>>>(
                slab, counts, rsl, sbase, ratio_f, rs_g, ratio_g, wx, wy);
            sparse_mv<1><<<blocks_p, THREADS, 0, stream>>>(
                slab, counts, rsl, sbase, ratio_g, rs_f, ratio_f, wx, wy);
        }
        ot_reduce_sp<<<NPROB, THREADS, 0, stream>>>(wx, wy, rs_f, rs_g, ot);
        combine<<<1, 64, 0, stream>>>(ot, out);
    } else {
        size_t need8 = ((size_t)2 * NPROB * 8 * PTS + NPROB) * sizeof(float);
        if (ws_size >= need8) run_dense<8>(x, y, wx, wy, out, d_ws, stream);
        else                  run_dense<4>(x, y, wx, wy, out, d_ws, stream);
    }
}

// Round 8
// 446.612 us; speedup vs baseline: 5.4676x; 1.7024x over previous
//
#include <hip/hip_runtime.h>
#include <hip/hip_fp16.h>

#define PTS     2048
#define NBATCH  8
#define NPROB   24          // 8 xy + 8 xx + 8 yy
#define NSTRUCT 32          // 24 originals + 8 yx transposes (for xy side-0)
#define THREADS 256
#define MAX_ITER 20

// k(x,y) = exp(-2*acos(min(|x.y|,1-1e-7))/0.05) = 2^(EXP_SCALE * acos(t))
#define EXP_SCALE (-57.70780163555853f)   // -(2/0.05)*log2(e)
#define EPS_LN2   (0.034657359027997264f) // 0.05 * ln(2)
#define CLIP      (0.9999999f)

// Sparsity cutoff: keep entries with L > -28  (theta < 28/57.7078 = 0.48520 rad)
// t > cos(0.48520) = 0.884580. Density (2/pi)(th - sin th cos th) ~ 4.62%.
// Error: rel row-sum err eps_r -> potential err = eps*eps_r (0.05x damping).
// typical culled/kept ~3e-7 (NN th~0.105), worst isolated row ~1e-4;
// f16-L quantization ~1e-3 rel on dominant entries -> total df ~ 1e-4 << 4e-3 thr.
#define T_CUT     (0.884580f)
#define CAP_ENTRIES (28u*1024u*1024u)     // 28M entries (expect ~6.2M) = 112 MB

// acos(t) = sqrt(1-t)*poly(t), |err| <= 6.8e-5 on [0,1] (A&S 4.4.45 4-term)
__device__ __forceinline__ float acos_poly(float t) {
    float p = -0.0187292994f;
    p = fmaf(p, t,  0.0742610022f);
    p = fmaf(p, t, -0.2121143937f);
    p = fmaf(p, t,  1.5707287550f);
    return p;
}

__device__ __forceinline__ unsigned short f32_to_f16bits(float f) {
    __half h = __float2half(f);
    return *reinterpret_cast<unsigned short*>(&h);
}
__device__ __forceinline__ float f16bits_to_f32(unsigned short u) {
    __half h = *reinterpret_cast<__half*>(&u);
    return __half2float(h);
}

// problem p: type=p>>3 (0:xy 1:xx 2:yy), batch n=p&7.
__device__ __forceinline__ void prob_w(int p, const float* wx, const float* wy,
                                       const float** wa, const float** wb) {
    int type = p >> 3, n = p & 7;
    *wa = ((type <= 1) ? wx : wy) + (size_t)n * PTS;
    *wb = ((type == 0) ? wy : ((type == 1) ? wx : wy)) + (size_t)n * PTS;
}

// structure s: s<24 -> CSR of K_p; s in [24,32) -> CSR of K_{yx,n} (transpose for xy side-0)
__device__ __forceinline__ void struct_ptrs(int s,
        const float* x, const float* y, const float** rowP, const float** colP) {
    if (s < 24) {
        int type = s >> 3, n = s & 7;
        *rowP = ((type <= 1) ? x : y) + (size_t)n * PTS * 4;
        *colP = ((type == 0) ? y : ((type == 1) ? x : y)) + (size_t)n * PTS * 4;
    } else {
        int n = s - 24;
        *rowP = y + (size_t)n * PTS * 4;
        *colP = x + (size_t)n * PTS * 4;
    }
}

// ---------------- sparse-cache path ----------------

// rs_f = 1, ratio_f = a  (f = 0 start)
__global__ void __launch_bounds__(THREADS) init_state(
        const float* __restrict__ wx, const float* __restrict__ wy,
        float* __restrict__ rs_f, float* __restrict__ ratio_f) {
    int i = blockIdx.x * THREADS + threadIdx.x;   // over NPROB*PTS
    int p = i / PTS, r = i % PTS;
    const float *wa, *wb;
    prob_w(p, wx, wy, &wa, &wb);
    rs_f[i] = 1.0f;
    ratio_f[i] = wa[r];
}

// 4 rows per wave: count columns with t > T_CUT.
// block = 16 rows of one struct; grid = NSTRUCT * 128
__global__ void __launch_bounds__(THREADS) count_kernel(
        const float* __restrict__ x, const float* __restrict__ y,
        unsigned* __restrict__ counts) {
    int s  = blockIdx.x >> 7;
    int rb = blockIdx.x & 127;
    int wv = threadIdx.x >> 6, lane = threadIdx.x & 63;
    const float *rowP, *colP;
    struct_ptrs(s, x, y, &rowP, &colP);
    int r0 = rb * 16 + wv * 4;
    float4 rp[4];
    unsigned cnt[4] = {0,0,0,0};
    #pragma unroll
    for (int i = 0; i < 4; ++i) rp[i] = reinterpret_cast<const float4*>(rowP)[r0 + i];
    for (int base = 0; base < PTS; base += 64) {
        float4 q = reinterpret_cast<const float4*>(colP)[base + lane];
        #pragma unroll
        for (int i = 0; i < 4; ++i) {
            float d = rp[i].x*q.x;
            d = fmaf(rp[i].y,q.y,d); d = fmaf(rp[i].z,q.z,d); d = fmaf(rp[i].w,q.w,d);
            float t = fminf(fabsf(d), CLIP);
            cnt[i] += (unsigned)__popcll(__ballot(t > T_CUT));
        }
    }
    if (lane == 0) {
        #pragma unroll
        for (int i = 0; i < 4; ++i) counts[s * PTS + r0 + i] = cnt[i];
    }
}

// exclusive scan of 2048 counts per structure -> row_start_local + struct_total
__global__ void __launch_bounds__(THREADS) scan_kernel(
        const unsigned* __restrict__ counts, unsigned* __restrict__ rsl,
        unsigned* __restrict__ stotal) {
    int s = blockIdx.x, tid = threadIdx.x;
    const unsigned* c = counts + (size_t)s * PTS;
    unsigned v[8], sum = 0;
    #pragma unroll
    for (int q = 0; q < 8; ++q) { v[q] = c[tid*8+q]; sum += v[q]; }
    __shared__ unsigned ts[THREADS];
    ts[tid] = sum; __syncthreads();
    for (int off = 1; off < THREADS; off <<= 1) {
        unsigned add = (tid >= off) ? ts[tid-off] : 0u;
        __syncthreads();
        ts[tid] += add; __syncthreads();
    }
    unsigned run = (tid == 0) ? 0u : ts[tid-1];
    unsigned* out = rsl + (size_t)s * PTS;
    #pragma unroll
    for (int q = 0; q < 8; ++q) { out[tid*8+q] = run; run += v[q]; }
    if (tid == THREADS-1) stotal[s] = ts[THREADS-1];
}

__global__ void base_kernel(const unsigned* __restrict__ stotal,
                            unsigned* __restrict__ sbase) {
    if (threadIdx.x == 0) {
        unsigned run = 0;
        for (int s = 0; s < NSTRUCT; ++s) { sbase[s] = run; run += stotal[s]; }
    }
}

// ordered compacted fill, 4 rows per wave: entry = (col_idx<<16) | f16(L)
__global__ void __launch_bounds__(THREADS) fill_kernel(
        const float* __restrict__ x, const float* __restrict__ y,
        const unsigned* __restrict__ rsl, const unsigned* __restrict__ sbase,
        unsigned* __restrict__ slab) {
    int s  = blockIdx.x >> 7;
    int rb = blockIdx.x & 127;
    int wv = threadIdx.x >> 6, lane = threadIdx.x & 63;
    const float *rowP, *colP;
    struct_ptrs(s, x, y, &rowP, &colP);
    int r0 = rb * 16 + wv * 4;
    float4 rp[4];
    unsigned off[4];
    #pragma unroll
    for (int i = 0; i < 4; ++i) {
        rp[i]  = reinterpret_cast<const float4*>(rowP)[r0 + i];
        off[i] = sbase[s] + rsl[s * PTS + r0 + i];
    }
    unsigned long long lt_mask = (1ull << lane) - 1ull;   // bits [0, lane)
    for (int base = 0; base < PTS; base += 64) {
        int j = base + lane;
        float4 q = reinterpret_cast<const float4*>(colP)[j];
        #pragma unroll
        for (int i = 0; i < 4; ++i) {
            float d = rp[i].x*q.x;
            d = fmaf(rp[i].y,q.y,d); d = fmaf(rp[i].z,q.z,d); d = fmaf(rp[i].w,q.w,d);
            float t = fminf(fabsf(d), CLIP);
            bool pass = t > T_CUT;
            unsigned long long bal = __ballot(pass);
            if (pass) {
                float sr = __builtin_amdgcn_sqrtf(1.0f - t);
                float L  = EXP_SCALE * (sr * acos_poly(t));
                unsigned pos = off[i] + (unsigned)__popcll(bal & lt_mask);
                if (pos < CAP_ENTRIES)
                    slab[pos] = ((unsigned)j << 16) | f32_to_f16bits(L);
            }
            off[i] += (unsigned)__popcll(bal);
        }
    }
}

// block = 32 rows of one problem; ratio table staged in LDS.
// Per wave: 8 rows INTERLEAVED (predicated clamped gathers) -> 8 loads in
// flight per iteration instead of sequential per-row load-wait chains.
template <int SIDE>
__global__ void __launch_bounds__(THREADS) sparse_mv(
        const unsigned* __restrict__ slab, const unsigned* __restrict__ counts,
        const unsigned* __restrict__ rsl, const unsigned* __restrict__ sbase,
        const float* __restrict__ ratio_src, float* __restrict__ rs_dst,
        float* __restrict__ ratio_dst,
        const float* __restrict__ wx, const float* __restrict__ wy) {
    __shared__ float lds_ratio[PTS];
    int p  = blockIdx.x >> 6;           // 64 row-blocks (32 rows) per problem
    int rb = blockIdx.x & 63;
    const float* rsrc = ratio_src + (size_t)p * PTS;
    for (int i = threadIdx.x; i < PTS/4; i += THREADS)
        reinterpret_cast<float4*>(lds_ratio)[i] = reinterpret_cast<const float4*>(rsrc)[i];
    __syncthreads();

    int wv = threadIdx.x >> 6, lane = threadIdx.x & 63;
    int s = (SIDE == 0) ? ((p < 8) ? 24 + p : p) : p;
    int r0 = rb * 32 + wv * 8;

    unsigned start[8], cnt[8], kmax = 0;
    #pragma unroll
    for (int i = 0; i < 8; ++i) {       // wave-uniform row descriptors
        start[i] = sbase[s] + rsl[s * PTS + r0 + i];
        cnt[i]   = counts[s * PTS + r0 + i];
        kmax = kmax > cnt[i] ? kmax : cnt[i];
    }

    float acc[8] = {0,0,0,0,0,0,0,0};
    for (unsigned k = lane; k < kmax; k += 64) {
        #pragma unroll
        for (int i = 0; i < 8; ++i) {   // 8 independent gathers issue together
            unsigned cn = cnt[i];
            unsigned kk = (k < cn) ? k : (cn ? cn - 1u : 0u);
            unsigned e  = slab[start[i] + kk];
            float kv = __builtin_amdgcn_exp2f(f16bits_to_f32((unsigned short)(e & 0xffffu)));
            float pr = lds_ratio[e >> 16];
            acc[i] += (k < cn) ? kv * pr : 0.0f;
        }
    }

    #pragma unroll
    for (int off = 32; off; off >>= 1) {    // 8 interleaved reduction chains
        #pragma unroll
        for (int i = 0; i < 8; ++i) acc[i] += __shfl_down(acc[i], off, 64);
    }
    if (lane == 0) {
        const float *wa, *wb;
        prob_w(p, wx, wy, &wa, &wb);
        #pragma unroll
        for (int i = 0; i < 8; ++i) {
            int r = r0 + i;
            float wrow = (SIDE == 0) ? wb[r] : wa[r];
            rs_dst[(size_t)p * PTS + r] = acc[i];
            ratio_dst[(size_t)p * PTS + r] = wrow / acc[i];
        }
    }
}

// OT_p = -eps*ln2*( sum_i a_i log2 rs_f_i + sum_j b_j log2 rs_g_j )
__global__ void __launch_bounds__(THREADS) ot_reduce_sp(
        const float* __restrict__ wx, const float* __restrict__ wy,
        const float* __restrict__ rs_f, const float* __restrict__ rs_g,
        float* __restrict__ ot) {
    int p = blockIdx.x;
    const float *wa, *wb;
    prob_w(p, wx, wy, &wa, &wb);
    const float* rf = rs_f + (size_t)p * PTS;
    const float* rg = rs_g + (size_t)p * PTS;
    float acc = 0.0f;
    for (int i = threadIdx.x; i < PTS; i += THREADS)
        acc += wa[i] * __builtin_amdgcn_logf(rf[i]) + wb[i] * __builtin_amdgcn_logf(rg[i]);
    for (int off = 32; off; off >>= 1) acc += __shfl_down(acc, off, 64);
    __shared__ float red[THREADS / 64];
    if ((threadIdx.x & 63) == 0) red[threadIdx.x >> 6] = acc;
    __syncthreads();
    if (threadIdx.x == 0)
        ot[p] = -EPS_LN2 * (red[0] + red[1] + red[2] + red[3]);
}

__global__ void combine(const float* __restrict__ ot, float* __restrict__ out) {
    if (threadIdx.x == 0) {
        float s = 0.0f;
        for (int n = 0; n < NBATCH; ++n)
            s += ot[n] - 0.5f * (ot[8 + n] + ot[16 + n]);
        out[0] = s / (float)NBATCH;
    }
}

// ---------------- dense fallback (r3 path, passed @1600us) ----------------

#define MRD     2
#define ROWSPB  (THREADS * MRD)
#define RGD     (PTS / ROWSPB)

template <int JCv>
__global__ void __launch_bounds__(THREADS) init_partials(float* __restrict__ partA) {
    int i = blockIdx.x * THREADS + threadIdx.x;
    int p = i / PTS, r = i % PTS;
    float* base = partA + (size_t)p * JCv * PTS;
    base[r] = 1.0f;
    #pragma unroll
    for (int c = 1; c < JCv; ++c) base[c * PTS + r] = 0.0f;
}

__device__ __forceinline__ void prob_pts(int p,
        const float* x, const float* y, const float** Xp, const float** Yp) {
    int type = p >> 3, n = p & 7;
    *Xp = ((type <= 1) ? x : y) + (size_t)n * PTS * 4;
    *Yp = ((type == 0) ? y : ((type == 1) ? x : y)) + (size_t)n * PTS * 4;
}

template <int JCv>
__global__ void __launch_bounds__(THREADS) half_update(
        const float* __restrict__ x,  const float* __restrict__ y,
        const float* __restrict__ wx, const float* __restrict__ wy,
        const float* __restrict__ part_in, float* __restrict__ part_out, int side)
{
    constexpr int CHUNK = PTS / JCv;
    __shared__ float4 cpts[CHUNK];
    __shared__ float  clw[CHUNK];
    int b = blockIdx.x;
    int p = b / (RGD * JCv);
    int rem = b % (RGD * JCv);
    int rg = rem / JCv, jc = rem % JCv;
    const float *Xp, *Yp, *wa, *wb;
    prob_pts(p, x, y, &Xp, &Yp);
    prob_w(p, wx, wy, &wa, &wb);
    const float* rowPts = (side == 0) ? Yp : Xp;
    const float* colPts = (side == 0) ? Xp : Yp;
    const float* wcol   = (side == 0) ? wa : wb;
    const float* pin = part_in + (size_t)p * JCv * PTS;
    for (int k = threadIdx.x; k < CHUNK; k += THREADS) {
        int j = jc * CHUNK + k;
        float s = 0.0f;
        #pragma unroll
        for (int c = 0; c < JCv; ++c) s += pin[c * PTS + j];
        clw[k]  = __builtin_amdgcn_logf(wcol[j]) - __builtin_amdgcn_logf(s);
        cpts[k] = reinterpret_cast<const float4*>(colPts)[j];
    }
    __syncthreads();
    int r0 = rg * ROWSPB + threadIdx.x;
    int r1 = r0 + THREADS;
    float4 ra = reinterpret_cast<const float4*>(rowPts)[r0];
    float4 rb = reinterpret_cast<const float4*>(rowPts)[r1];
    float acc0 = 0.0f, acc1 = 0.0f;
    #pragma unroll 4
    for (int k = 0; k < CHUNK; ++k) {
        float4 q = cpts[k];
        float lw = clw[k];
        float d0 = ra.x*q.x, d1 = rb.x*q.x;
        d0 = fmaf(ra.y,q.y,d0);  d1 = fmaf(rb.y,q.y,d1);
        d0 = fmaf(ra.z,q.z,d0);  d1 = fmaf(rb.z,q.z,d1);
        d0 = fmaf(ra.w,q.w,d0);  d1 = fmaf(rb.w,q.w,d1);
        float t0 = fminf(fabsf(d0), CLIP), t1 = fminf(fabsf(d1), CLIP);
        float s0 = __builtin_amdgcn_sqrtf(1.0f - t0);
        float s1 = __builtin_amdgcn_sqrtf(1.0f - t1);
        float A0 = s0 * acos_poly(t0), A1 = s1 * acos_poly(t1);
        acc0 += __builtin_amdgcn_exp2f(fmaf(A0, EXP_SCALE, lw));
        acc1 += __builtin_amdgcn_exp2f(fmaf(A1, EXP_SCALE, lw));
    }
    float* pout = part_out + ((size_t)p * JCv + jc) * PTS;
    pout[r0] = acc0;
    pout[r1] = acc1;
}

template <int JCv>
__global__ void __launch_bounds__(THREADS) ot_reduce_d(
        const float* __restrict__ wx, const float* __restrict__ wy,
        const float* __restrict__ partA, const float* __restrict__ partB,
        float* __restrict__ ot)
{
    int p = blockIdx.x;
    const float *wa, *wb;
    prob_w(p, wx, wy, &wa, &wb);
    const float* pa = partA + (size_t)p * JCv * PTS;
    const float* pb = partB + (size_t)p * JCv * PTS;
    float acc = 0.0f;
    for (int i = threadIdx.x; i < PTS; i += THREADS) {
        float rsA = 0.0f, rsB = 0.0f;
        #pragma unroll
        for (int c = 0; c < JCv; ++c) { rsA += pa[c*PTS+i]; rsB += pb[c*PTS+i]; }
        acc += wa[i] * __builtin_amdgcn_logf(rsA) + wb[i] * __builtin_amdgcn_logf(rsB);
    }
    for (int off = 32; off; off >>= 1) acc += __shfl_down(acc, off, 64);
    __shared__ float red[THREADS / 64];
    if ((threadIdx.x & 63) == 0) red[threadIdx.x >> 6] = acc;
    __syncthreads();
    if (threadIdx.x == 0)
        ot[p] = -EPS_LN2 * (red[0] + red[1] + red[2] + red[3]);
}

template <int JCv>
static void run_dense(const float* x, const float* y, const float* wx, const float* wy,
                      float* out, void* d_ws, hipStream_t stream)
{
    float* partA = (float*)d_ws;
    float* partB = partA + (size_t)NPROB * JCv * PTS;
    float* ot    = partB + (size_t)NPROB * JCv * PTS;
    init_partials<JCv><<<NPROB * PTS / THREADS, THREADS, 0, stream>>>(partA);
    for (int it = 0; it < MAX_ITER; ++it) {
        half_update<JCv><<<NPROB * RGD * JCv, THREADS, 0, stream>>>(x, y, wx, wy, partA, partB, 0);
        half_update<JCv><<<NPROB * RGD * JCv, THREADS, 0, stream>>>(x, y, wx, wy, partB, partA, 1);
    }
    ot_reduce_d<JCv><<<NPROB, THREADS, 0, stream>>>(wx, wy, partA, partB, ot);
    combine<<<1, 64, 0, stream>>>(ot, out);
}

// ---------------- launcher ----------------

extern "C" void kernel_launch(void* const* d_in, const int* in_sizes, int n_in,
                              void* d_out, int out_size, void* d_ws, size_t ws_size,
                              hipStream_t stream)
{
    // setup_inputs dict order: y, w_y, x, w_x
    const float* y  = (const float*)d_in[0];
    const float* wy = (const float*)d_in[1];
    const float* x  = (const float*)d_in[2];
    const float* wx = (const float*)d_in[3];
    float* out = (float*)d_out;

    // sparse ws layout
    size_t off = 0;
    unsigned* slab   = (unsigned*)d_ws;          off += (size_t)CAP_ENTRIES * 4;
    unsigned* counts = (unsigned*)((char*)d_ws + off); off += (size_t)NSTRUCT * PTS * 4;
    unsigned* rsl    = (unsigned*)((char*)d_ws + off); off += (size_t)NSTRUCT * PTS * 4;
    unsigned* stotal = (unsigned*)((char*)d_ws + off); off += 64 * 4;
    unsigned* sbase  = (unsigned*)((char*)d_ws + off); off += 64 * 4;
    float* rs_f    = (float*)((char*)d_ws + off); off += (size_t)NPROB * PTS * 4;
    float* rs_g    = (float*)((char*)d_ws + off); off += (size_t)NPROB * PTS * 4;
    float* ratio_f = (float*)((char*)d_ws + off); off += (size_t)NPROB * PTS * 4;
    float* ratio_g = (float*)((char*)d_ws + off); off += (size_t)NPROB * PTS * 4;
    float* ot      = (float*)((char*)d_ws + off); off += 64 * 4;

    if (ws_size >= off) {
        int blocks_s = NSTRUCT * (PTS / 16);   // 16 rows/block (4 rows/wave)
        int blocks_p = NPROB * (PTS / 32);     // 32 rows/block (8 rows/wave)
        init_state<<<NPROB * PTS / THREADS, THREADS, 0, stream>>>(wx, wy, rs_f, ratio_f);
        count_kernel<<<blocks_s, THREADS, 0, stream>>>(x, y, counts);
        scan_kernel<<<NSTRUCT, THREADS, 0, stream>>>(counts, rsl, stotal);
        base_kernel<<<1, 64, 0, stream>>>(stotal, sbase);
        fill_kernel<<<blocks_s, THREADS, 0, stream>>>(x, y, rsl, sbase, slab);
        for (int it = 0; it < MAX_ITER; ++it) {
            sparse_mv<0><<<blocks_p, THREADS, 0, stream>>>(
                slab, counts, rsl, sbase, ratio_f, rs_g, ratio_g, wx, wy);
            sparse_mv<1><<<blocks_p, THREADS, 0, stream>>>(
                slab, counts, rsl, sbase, ratio_g, rs_f, ratio_f, wx, wy);
        }
        ot_reduce_sp<<<NPROB, THREADS, 0, stream>>>(wx, wy, rs_f, rs_g, ot);
        combine<<<1, 64, 0, stream>>>(ot, out);
    } else {
        size_t need8 = ((size_t)2 * NPROB * 8 * PTS + NPROB) * sizeof(float);
        if (ws_size >= need8) run_dense<8>(x, y, wx, wy, out, d_ws, stream);
        else                  run_dense<4>(x, y, wx, wy, out, d_ws, stream);
    }
}